// Round 1
// baseline (570.322 us; speedup 1.0000x reference)
//
#include <hip/hip_runtime.h>
#include <hip/hip_bf16.h>

#define B_   1024
#define T_   85
#define DIN  20
#define H_   1024
#define C_   27
#define OBJ_ (T_ * 36)   // 3060
#define TOUT (T_ - 1)    // 84

// ---------------------------------------------------------------------------
// Generic fp32 register-tiled GEMM: C[M,N] = act(A[M,K] @ B[K,N] + bias[N])
// BM=BN=64, BK=16, 256 threads, 4x4 thread tile. Grid = (N/64, M/64).
// ---------------------------------------------------------------------------
template <int RELU>
__global__ __launch_bounds__(256) void gemm_rt(
    const float* __restrict__ A, const float* __restrict__ Bm,
    const float* __restrict__ bias, float* __restrict__ C,
    int M, int N, int K)
{
    __shared__ float As[16][64];   // As[k][m] (A tile transposed)
    __shared__ float Bs[16][64];   // Bs[k][n]

    const int tid = threadIdx.x;
    const int bm  = blockIdx.y * 64;
    const int bn  = blockIdx.x * 64;
    const int tx  = tid & 15;      // n-group
    const int ty  = tid >> 4;      // m-group
    const int am  = tid >> 2, akq = tid & 3;   // A-tile load mapping
    const int bk  = tid >> 4, bnq = tid & 15;  // B-tile load mapping

    float acc[4][4] = {};

    for (int k0 = 0; k0 < K; k0 += 16) {
        // load A tile (64 rows x 16 k), transposed into LDS
        const int ak = k0 + akq * 4;
        const float* Ap = A + (long)(bm + am) * K + ak;
        float4 av;
        if (ak + 3 < K) {
            av = *(const float4*)Ap;
        } else {
            av.x = (ak + 0 < K) ? Ap[0] : 0.f;
            av.y = (ak + 1 < K) ? Ap[1] : 0.f;
            av.z = (ak + 2 < K) ? Ap[2] : 0.f;
            av.w = (ak + 3 < K) ? Ap[3] : 0.f;
        }
        As[akq * 4 + 0][am] = av.x;
        As[akq * 4 + 1][am] = av.y;
        As[akq * 4 + 2][am] = av.z;
        As[akq * 4 + 3][am] = av.w;

        // load B tile (16 k x 64 n)
        float4 bv = make_float4(0.f, 0.f, 0.f, 0.f);
        if (k0 + bk < K)
            bv = *(const float4*)(Bm + (long)(k0 + bk) * N + bn + bnq * 4);
        *(float4*)&Bs[bk][bnq * 4] = bv;

        __syncthreads();

#pragma unroll
        for (int kk = 0; kk < 16; ++kk) {
            float ar[4], br[4];
            *(float4*)ar = *(const float4*)&As[kk][ty * 4];
            *(float4*)br = *(const float4*)&Bs[kk][tx * 4];
#pragma unroll
            for (int r = 0; r < 4; ++r)
#pragma unroll
                for (int c = 0; c < 4; ++c)
                    acc[r][c] = fmaf(ar[r], br[c], acc[r][c]);
        }
        __syncthreads();
    }

#pragma unroll
    for (int r = 0; r < 4; ++r) {
        const int row = bm + ty * 4 + r;
#pragma unroll
        for (int c = 0; c < 4; ++c) {
            const int col = bn + tx * 4 + c;
            float v = acc[r][c] + bias[col];
            if (RELU) v = fmaxf(v, 0.f);
            C[(long)row * N + col] = v;
        }
    }
}

// ---------------------------------------------------------------------------
// Fused sequential expert kernel. One block per batch row b.
// hpre[j] = base[b,j] + cur0*eW1[0,j] + sum_{d=1..19} x[b,t,d]*eW1[d,j]
// out[b,t,c] = sum_j relu(hpre[j]) * eW2[j,c] + eb2[c];  prev = out[b,t,0]
// Thread owns j = 4*tid .. 4*tid+3; eW1 rows 0..19 and eW2 rows in registers.
// 27-channel cross-thread reduction via two-stage LDS transpose (stride 29,
// conflict-free).
// ---------------------------------------------------------------------------
__global__ __launch_bounds__(256, 2) void expert_seq(
    const float* __restrict__ x,    // [B, T, DIN]
    const float* __restrict__ eW1,  // [DIN+H, H] (rows 0..19 used here)
    const float* __restrict__ eW2,  // [H, C]
    const float* __restrict__ eb2,  // [C]
    const float* __restrict__ base, // [B, H]  (objInfo @ eW1[20:] + eb1)
    float* __restrict__ out)        // [B, TOUT, C]
{
    const int b   = blockIdx.x;
    const int tid = threadIdx.x;
    const int j0  = tid * 4;

    __shared__ float xl[T_ * DIN];     // 1700 floats
    __shared__ float pl[256 * 29];     // stage-1 partials (stride 29: gcd(29,32)=1)
    __shared__ float pl2[256];         // stage-2 partials
    __shared__ float prevs;

    for (int idx = tid; idx < T_ * DIN; idx += 256)
        xl[idx] = x[(long)b * (T_ * DIN) + idx];

    float w1r[DIN][4];
#pragma unroll
    for (int d = 0; d < DIN; ++d)
        *(float4*)w1r[d] = *(const float4*)&eW1[(long)d * H_ + j0];

    float base_r[4];
    *(float4*)base_r = *(const float4*)&base[(long)b * H_ + j0];

    float w2r[4][C_];
#pragma unroll
    for (int i = 0; i < 4; ++i)
#pragma unroll
        for (int c = 0; c < C_; ++c)
            w2r[i][c] = eW2[(long)(j0 + i) * C_ + c];

    const float myb = (tid < C_) ? eb2[tid] : 0.f;
    __syncthreads();

    float prev = 0.f;
#pragma unroll 1
    for (int t = 0; t < TOUT; ++t) {
        const float cur0 = (t == 0) ? xl[0] : prev;

        float h[4];
#pragma unroll
        for (int i = 0; i < 4; ++i)
            h[i] = fmaf(cur0, w1r[0][i], base_r[i]);
#pragma unroll
        for (int d = 1; d < DIN; ++d) {
            const float xv = xl[t * DIN + d];
#pragma unroll
            for (int i = 0; i < 4; ++i)
                h[i] = fmaf(xv, w1r[d][i], h[i]);
        }
#pragma unroll
        for (int i = 0; i < 4; ++i)
            h[i] = fmaxf(h[i], 0.f);

        float p[C_];
#pragma unroll
        for (int c = 0; c < C_; ++c)
            p[c] = h[0] * w2r[0][c];
#pragma unroll
        for (int i = 1; i < 4; ++i)
#pragma unroll
            for (int c = 0; c < C_; ++c)
                p[c] = fmaf(h[i], w2r[i][c], p[c]);

        // stage 1: write 27 partials per thread (stride 29 -> conflict-free)
#pragma unroll
        for (int c = 0; c < C_; ++c)
            pl[tid * 29 + c] = p[c];
        __syncthreads();

        // stage 2: thread (grp, c2) sums partials of threads grp*32..grp*32+31
        {
            const int c2 = tid & 31, grp = tid >> 5;
            float s = 0.f;
            if (c2 < C_) {
                const int basei = grp * 32 * 29 + c2;
#pragma unroll
                for (int s2 = 0; s2 < 32; ++s2)
                    s += pl[basei + s2 * 29];
            }
            pl2[tid] = s;
        }
        __syncthreads();

        // stage 3: 27 threads finish, write output, thread 0 publishes prev
        if (tid < C_) {
            float o = myb;
#pragma unroll
            for (int g = 0; g < 8; ++g)
                o += pl2[g * 32 + tid];
            out[((long)b * TOUT + t) * C_ + tid] = o;
            if (tid == 0) prevs = o;
        }
        __syncthreads();
        prev = prevs;
    }
}

// ---------------------------------------------------------------------------
extern "C" void kernel_launch(void* const* d_in, const int* in_sizes, int n_in,
                              void* d_out, int out_size, void* d_ws, size_t ws_size,
                              hipStream_t stream)
{
    const float* o   = (const float*)d_in[0];  // [B, OBJ]
    const float* x   = (const float*)d_in[1];  // [B, T, DIN]
    const float* oW1 = (const float*)d_in[2];  // [OBJ, H]
    const float* ob1 = (const float*)d_in[3];  // [H]
    const float* oW2 = (const float*)d_in[4];  // [H, H]
    const float* ob2 = (const float*)d_in[5];  // [H]
    const float* eW1 = (const float*)d_in[6];  // [DIN+H, H]
    const float* eb1 = (const float*)d_in[7];  // [H]
    const float* eW2 = (const float*)d_in[8];  // [H, C]
    const float* eb2 = (const float*)d_in[9];  // [C]

    float* outp = (float*)d_out;
    float* ws   = (float*)d_ws;

    float* h1   = ws;                          // [B, H]  4 MB
    float* obj  = ws + (size_t)B_ * H_;        // [B, H]  4 MB
    float* base = ws + 2 * (size_t)B_ * H_;    // [B, H]  4 MB

    dim3 blk(256);
    dim3 g16(H_ / 64, B_ / 64);  // (16,16) = 256 blocks

    // h1 = relu(o @ oW1 + ob1)
    gemm_rt<1><<<g16, blk, 0, stream>>>(o, oW1, ob1, h1, B_, H_, OBJ_);
    // obj = h1 @ oW2 + ob2
    gemm_rt<0><<<g16, blk, 0, stream>>>(h1, oW2, ob2, obj, B_, H_, H_);
    // base = obj @ eW1[20:,:] + eb1   (step-invariant part of expert layer 1)
    gemm_rt<0><<<g16, blk, 0, stream>>>(obj, eW1 + (long)DIN * H_, eb1, base,
                                        B_, H_, H_);
    // sequential recurrence + full 27-channel outputs
    expert_seq<<<dim3(B_), blk, 0, stream>>>(x, eW1, eW2, eb2, base, outp);
}

// Round 2
// 443.809 us; speedup vs baseline: 1.2851x; 1.2851x over previous
//
#include <hip/hip_runtime.h>
#include <hip/hip_bf16.h>

#define B_   1024
#define T_   85
#define DIN  20
#define H_   1024
#define C_   27
#define OBJ_ (T_ * 36)   // 3060
#define TOUT (T_ - 1)    // 84

// ---------------------------------------------------------------------------
// GEMM v2 core: C[64x64 tile] = act(A @ B + bias [+ bias_parts]) .
// BK=16, 256 threads, 4x4 per thread, wave-local 8x8 lane grid,
// single-barrier LDS double-buffer with register prefetch.
// As padded stride 68: store 2-way (free), reads conflict-free.
// ---------------------------------------------------------------------------
struct GemmSmem {
    float As[2][16][68];
    float Bs[2][16][64];
};

template <int RELU>
__device__ __forceinline__ void gemm_core(
    const float* __restrict__ A, int lda,
    const float* __restrict__ Bm, int ldb,
    const float* __restrict__ bias,        // may be null
    const float* __restrict__ bias_parts,  // [8][H_] partials, may be null
    float* __restrict__ Cc, int ldc,
    int K, int tile, GemmSmem& sm)
{
    const int tid = threadIdx.x;
    const int bm  = (tile >> 4) * 64;
    const int bn  = (tile & 15) * 64;

    const int wave = tid >> 6;
    const int l    = tid & 63;
    const int n0   = (wave & 1) * 32 + (l & 7) * 4;
    const int m0   = (wave >> 1) * 32 + (l >> 3) * 4;

    const int am  = tid >> 2, akq = tid & 3;   // A load: 16 rows x 64B/wave
    const int bk  = tid >> 4, bnq = tid & 15;  // B load: row-contig

    const float* Arow = A + (long)(bm + am) * lda + akq * 4;
    const float* Brow = Bm + (long)bk * ldb + bn + bnq * 4;

    float acc[4][4] = {};
    const int nIter = (K + 15) >> 4;

    // prologue: tile 0 -> LDS buf 0
    {
        const int ak = akq * 4;
        float4 av = (ak + 4 <= K) ? *(const float4*)(Arow)
                                  : make_float4(0.f, 0.f, 0.f, 0.f);
        float4 bv = (bk < K) ? *(const float4*)(Brow)
                             : make_float4(0.f, 0.f, 0.f, 0.f);
        sm.As[0][akq * 4 + 0][am] = av.x;
        sm.As[0][akq * 4 + 1][am] = av.y;
        sm.As[0][akq * 4 + 2][am] = av.z;
        sm.As[0][akq * 4 + 3][am] = av.w;
        *(float4*)&sm.Bs[0][bk][bnq * 4] = bv;
    }
    __syncthreads();

    for (int it = 0; it < nIter; ++it) {
        const int cur = it & 1;
        const bool pf = (it + 1 < nIter);
        float4 pav, pbv;
        if (pf) {  // issue next-tile loads before compute (latency hides)
            const int k0 = (it + 1) << 4;
            const int ak = k0 + akq * 4;
            pav = (ak + 4 <= K) ? *(const float4*)(Arow + k0)
                                : make_float4(0.f, 0.f, 0.f, 0.f);
            pbv = (k0 + bk < K) ? *(const float4*)(Brow + (long)k0 * ldb)
                                : make_float4(0.f, 0.f, 0.f, 0.f);
        }
#pragma unroll
        for (int kk = 0; kk < 16; ++kk) {
            float ar[4], br[4];
            *(float4*)ar = *(const float4*)&sm.As[cur][kk][m0];
            *(float4*)br = *(const float4*)&sm.Bs[cur][kk][n0];
#pragma unroll
            for (int r = 0; r < 4; ++r)
#pragma unroll
                for (int c = 0; c < 4; ++c)
                    acc[r][c] = fmaf(ar[r], br[c], acc[r][c]);
        }
        if (pf) {
            const int nb = cur ^ 1;
            sm.As[nb][akq * 4 + 0][am] = pav.x;
            sm.As[nb][akq * 4 + 1][am] = pav.y;
            sm.As[nb][akq * 4 + 2][am] = pav.z;
            sm.As[nb][akq * 4 + 3][am] = pav.w;
            *(float4*)&sm.Bs[nb][bk][bnq * 4] = pbv;
        }
        __syncthreads();
    }

    // epilogue
    float bias4[4];
#pragma unroll
    for (int c = 0; c < 4; ++c) {
        const int col = bn + n0 + c;
        float b = bias ? bias[col] : 0.f;
        if (bias_parts) {
#pragma unroll
            for (int p = 0; p < 8; ++p) b += bias_parts[p * H_ + col];
        }
        bias4[c] = b;
    }
#pragma unroll
    for (int r = 0; r < 4; ++r) {
        float4 v;
        float* vp = (float*)&v;
#pragma unroll
        for (int c = 0; c < 4; ++c) {
            float t = acc[r][c] + bias4[c];
            if (RELU) t = fmaxf(t, 0.f);
            vp[c] = t;
        }
        *(float4*)&Cc[(long)(bm + m0 + r) * ldc + bn + n0] = v;
    }
}

// ---------------------------------------------------------------------------
// Kernel A: blocks 0..255  -> h1 = relu(o @ oW1 + ob1)          [K=3060]
//           blocks 256..511-> Wc = oW2 @ eW1[20:]               [K=1024]
//           blocks 512..543-> biasc[kc][n] = partial of ob2 @ eW1[20:]
// Independent work fused into one launch => ~2 blocks/CU.
// ---------------------------------------------------------------------------
__global__ __launch_bounds__(256) void kernelA(
    const float* __restrict__ o,   const float* __restrict__ oW1,
    const float* __restrict__ ob1, const float* __restrict__ oW2,
    const float* __restrict__ eW1, const float* __restrict__ ob2,
    float* __restrict__ h1, float* __restrict__ Wc, float* __restrict__ biasc)
{
    __shared__ GemmSmem sm;
    const int bid = blockIdx.x;
    if (bid < 256) {
        gemm_core<1>(o, OBJ_, oW1, H_, ob1, nullptr, h1, H_, OBJ_, bid, sm);
    } else if (bid < 512) {
        gemm_core<0>(oW2, H_, eW1 + (long)DIN * H_, H_, nullptr, nullptr,
                     Wc, H_, H_, bid - 256, sm);
    } else {
        const int r = bid - 512, kc = r >> 2, nb = r & 3;
        const int n = nb * 256 + (int)threadIdx.x;
        const int k0 = kc * 128;
        float acc = 0.f;
#pragma unroll 8
        for (int k = 0; k < 128; ++k)
            acc = fmaf(ob2[k0 + k], eW1[(long)(DIN + k0 + k) * H_ + n], acc);
        biasc[kc * H_ + n] = acc;
    }
}

// ---------------------------------------------------------------------------
// Kernel B: base = h1 @ Wc + (eb1 + sum biasc)   [optionally split-K2]
// ---------------------------------------------------------------------------
__global__ __launch_bounds__(256) void kernelB(
    const float* __restrict__ h1, const float* __restrict__ Wc,
    const float* __restrict__ eb1, const float* __restrict__ biasc,
    float* __restrict__ base0, float* __restrict__ base1, int split)
{
    __shared__ GemmSmem sm;
    const int bid = blockIdx.x;
    if (!split) {
        gemm_core<0>(h1, H_, Wc, H_, eb1, biasc, base0, H_, H_, bid, sm);
    } else if (bid < 256) {
        gemm_core<0>(h1, H_, Wc, H_, eb1, biasc, base0, H_, 512, bid, sm);
    } else {
        gemm_core<0>(h1 + 512, H_, Wc + (long)512 * H_, H_, nullptr, nullptr,
                     base1, H_, 512, bid - 256, sm);
    }
}

// ---------------------------------------------------------------------------
// Fused sequential expert kernel (unchanged structure; base may be split).
// ---------------------------------------------------------------------------
__global__ __launch_bounds__(256, 2) void expert_seq(
    const float* __restrict__ x,    // [B, T, DIN]
    const float* __restrict__ eW1,  // rows 0..19 used
    const float* __restrict__ eW2,  // [H, C]
    const float* __restrict__ eb2,  // [C]
    const float* __restrict__ base0,
    const float* __restrict__ base1,  // may be null
    float* __restrict__ out)
{
    const int b   = blockIdx.x;
    const int tid = threadIdx.x;
    const int j0  = tid * 4;

    __shared__ float xl[T_ * DIN];
    __shared__ float pl[256 * 29];
    __shared__ float pl2[256];
    __shared__ float prevs;

    for (int idx = tid; idx < T_ * DIN; idx += 256)
        xl[idx] = x[(long)b * (T_ * DIN) + idx];

    float w1r[DIN][4];
#pragma unroll
    for (int d = 0; d < DIN; ++d)
        *(float4*)w1r[d] = *(const float4*)&eW1[(long)d * H_ + j0];

    float base_r[4];
    *(float4*)base_r = *(const float4*)&base0[(long)b * H_ + j0];
    if (base1) {
        float4 b1 = *(const float4*)&base1[(long)b * H_ + j0];
        base_r[0] += b1.x; base_r[1] += b1.y;
        base_r[2] += b1.z; base_r[3] += b1.w;
    }

    float w2r[4][C_];
#pragma unroll
    for (int i = 0; i < 4; ++i)
#pragma unroll
        for (int c = 0; c < C_; ++c)
            w2r[i][c] = eW2[(long)(j0 + i) * C_ + c];

    const float myb = (tid < C_) ? eb2[tid] : 0.f;
    __syncthreads();

    float prev = 0.f;
#pragma unroll 1
    for (int t = 0; t < TOUT; ++t) {
        const float cur0 = (t == 0) ? xl[0] : prev;

        float h[4];
#pragma unroll
        for (int i = 0; i < 4; ++i)
            h[i] = fmaf(cur0, w1r[0][i], base_r[i]);
#pragma unroll
        for (int d = 1; d < DIN; ++d) {
            const float xv = xl[t * DIN + d];
#pragma unroll
            for (int i = 0; i < 4; ++i)
                h[i] = fmaf(xv, w1r[d][i], h[i]);
        }
#pragma unroll
        for (int i = 0; i < 4; ++i)
            h[i] = fmaxf(h[i], 0.f);

        float p[C_];
#pragma unroll
        for (int c = 0; c < C_; ++c)
            p[c] = h[0] * w2r[0][c];
#pragma unroll
        for (int i = 1; i < 4; ++i)
#pragma unroll
            for (int c = 0; c < C_; ++c)
                p[c] = fmaf(h[i], w2r[i][c], p[c]);

#pragma unroll
        for (int c = 0; c < C_; ++c)
            pl[tid * 29 + c] = p[c];
        __syncthreads();

        {
            const int c2 = tid & 31, grp = tid >> 5;
            float s = 0.f;
            if (c2 < C_) {
                const int basei = grp * 32 * 29 + c2;
#pragma unroll
                for (int s2 = 0; s2 < 32; ++s2)
                    s += pl[basei + s2 * 29];
            }
            pl2[tid] = s;
        }
        __syncthreads();

        if (tid < C_) {
            float o = myb;
#pragma unroll
            for (int g = 0; g < 8; ++g)
                o += pl2[g * 32 + tid];
            out[((long)b * TOUT + t) * C_ + tid] = o;
            if (tid == 0) prevs = o;
        }
        __syncthreads();
        prev = prevs;
    }
}

// ---------------------------------------------------------------------------
extern "C" void kernel_launch(void* const* d_in, const int* in_sizes, int n_in,
                              void* d_out, int out_size, void* d_ws, size_t ws_size,
                              hipStream_t stream)
{
    const float* o   = (const float*)d_in[0];
    const float* x   = (const float*)d_in[1];
    const float* oW1 = (const float*)d_in[2];
    const float* ob1 = (const float*)d_in[3];
    const float* oW2 = (const float*)d_in[4];
    const float* ob2 = (const float*)d_in[5];
    const float* eW1 = (const float*)d_in[6];
    const float* eb1 = (const float*)d_in[7];
    const float* eW2 = (const float*)d_in[8];
    const float* eb2 = (const float*)d_in[9];

    float* outp = (float*)d_out;
    float* ws   = (float*)d_ws;

    const size_t MF = (size_t)H_ * H_;   // 1M floats = 4MB
    float* h1    = ws;
    float* Wc    = ws + MF;
    float* base0 = ws + 2 * MF;
    const int split = (ws_size >= (4 * MF + 16) * sizeof(float)) ? 1 : 0;
    float* base1 = split ? (ws + 3 * MF) : nullptr;

    // biasc staged in d_out head: written by kernelA, read by kernelB,
    // fully overwritten by expert_seq afterwards (deterministic).
    float* biasc = outp;   // 8*H_ floats << out_size (2.3M floats)

    dim3 blk(256);
    kernelA<<<dim3(544), blk, 0, stream>>>(o, oW1, ob1, oW2, eW1, ob2,
                                           h1, Wc, biasc);
    kernelB<<<dim3(split ? 512 : 256), blk, 0, stream>>>(h1, Wc, eb1, biasc,
                                                         base0, base1, split);
    expert_seq<<<dim3(B_), blk, 0, stream>>>(x, eW1, eW2, eb2, base0, base1,
                                             outp);
}

// Round 3
// 318.960 us; speedup vs baseline: 1.7881x; 1.3914x over previous
//
#include <hip/hip_runtime.h>
#include <hip/hip_bf16.h>

#define B_   1024
#define T_   85
#define DIN  20
#define H_   1024
#define C_   27
#define OBJ_ (T_ * 36)   // 3060
#define TOUT (T_ - 1)    // 84

typedef unsigned short u16;
typedef __attribute__((ext_vector_type(8))) short bf16x8;
typedef __attribute__((ext_vector_type(4))) float f32x4;

__device__ __forceinline__ u16 f2bf(float f) {
    __hip_bfloat16 h = __float2bfloat16(f);
    return *reinterpret_cast<u16*>(&h);
}
__device__ __forceinline__ float bf2f(u16 u) {
    __hip_bfloat16 h;
    *reinterpret_cast<u16*>(&h) = u;
    return __bfloat162float(h);
}

// ===========================================================================
// MFMA PATH
// ===========================================================================

// ---------------------------------------------------------------------------
// convertK: block ranges
//  [0,512)    o [1024][3060] f32 -> oh/ol [1024][3072] bf16 (split, pad 0)
//  [512,1280) oW1 [3060][1024] -> bW1t [1024 n][3072 k] bf16 (transpose)
//  [1280,1536) eW1[20:] [1024][1024] -> bE1t [1024][1024] bf16 (transpose)
//  [1536,1664) oW2 [1024][1024] -> o2h/o2l bf16 (split)
// ---------------------------------------------------------------------------
__global__ __launch_bounds__(256) void convertK(
    const float* __restrict__ o, const float* __restrict__ oW1,
    const float* __restrict__ eW1, const float* __restrict__ oW2,
    u16* __restrict__ oh, u16* __restrict__ ol, u16* __restrict__ bW1t,
    u16* __restrict__ bE1t, u16* __restrict__ o2h, u16* __restrict__ o2l)
{
    __shared__ float tl[64][65];
    const int bid = blockIdx.x, t = threadIdx.x;

    if (bid < 512) {
        for (int it = 0; it < 6; ++it) {
            const int idx = (bid * 256 + t) + it * 131072;
            const int row = idx / 768, g = idx - row * 768;
            float4 v = make_float4(0.f, 0.f, 0.f, 0.f);
            if (g < 765) v = *(const float4*)(o + (size_t)row * 3060 + g * 4);
            const float* vp = (const float*)&v;
            ushort4 uh, ul;
            u16 H[4], L[4];
#pragma unroll
            for (int j = 0; j < 4; ++j) {
                H[j] = f2bf(vp[j]);
                L[j] = f2bf(vp[j] - bf2f(H[j]));
            }
            uh.x = H[0]; uh.y = H[1]; uh.z = H[2]; uh.w = H[3];
            ul.x = L[0]; ul.y = L[1]; ul.z = L[2]; ul.w = L[3];
            *(ushort4*)(oh + (size_t)row * 3072 + g * 4) = uh;
            *(ushort4*)(ol + (size_t)row * 3072 + g * 4) = ul;
        }
    } else if (bid < 1536) {
        // transpose-convert: oW1 (768 tiles) or eW1' (256 tiles)
        const bool isW1 = (bid < 1280);
        const int idx = isW1 ? (bid - 512) : (bid - 1280);
        const int k0 = (idx >> 4) * 64, n0 = (idx & 15) * 64;
        const float* src = isW1 ? oW1 : (eW1 + (size_t)DIN * H_);
        const int Ksrc = isW1 ? 3060 : 1024;
        u16* dst = isW1 ? bW1t : bE1t;
        const int ldk = isW1 ? 3072 : 1024;
#pragma unroll
        for (int r = 0; r < 4; ++r) {
            const int k = k0 + r * 16 + (t >> 4);
            float4 v = make_float4(0.f, 0.f, 0.f, 0.f);
            if (k < Ksrc)
                v = *(const float4*)(src + (size_t)k * 1024 + n0 + (t & 15) * 4);
            const float* vp = (const float*)&v;
#pragma unroll
            for (int j = 0; j < 4; ++j)
                tl[r * 16 + (t >> 4)][(t & 15) * 4 + j] = vp[j];
        }
        __syncthreads();
#pragma unroll
        for (int r = 0; r < 4; ++r) {
            const int n = r * 16 + (t >> 4);
            ushort4 u;
            u.x = f2bf(tl[(t & 15) * 4 + 0][n]);
            u.y = f2bf(tl[(t & 15) * 4 + 1][n]);
            u.z = f2bf(tl[(t & 15) * 4 + 2][n]);
            u.w = f2bf(tl[(t & 15) * 4 + 3][n]);
            *(ushort4*)(dst + (size_t)(n0 + n) * ldk + k0 + (t & 15) * 4) = u;
        }
    } else {
        const int base = (bid - 1536) * 256 + t;
#pragma unroll
        for (int it = 0; it < 8; ++it) {
            const int g = base + it * 32768;
            float4 v = *(const float4*)(oW2 + (size_t)g * 4);
            const float* vp = (const float*)&v;
            ushort4 uh, ul;
            u16 H[4], L[4];
#pragma unroll
            for (int j = 0; j < 4; ++j) {
                H[j] = f2bf(vp[j]);
                L[j] = f2bf(vp[j] - bf2f(H[j]));
            }
            uh.x = H[0]; uh.y = H[1]; uh.z = H[2]; uh.w = H[3];
            ul.x = L[0]; ul.y = L[1]; ul.z = L[2]; ul.w = L[3];
            *(ushort4*)(o2h + (size_t)g * 4) = uh;
            *(ushort4*)(o2l + (size_t)g * 4) = ul;
        }
    }
}

// ---------------------------------------------------------------------------
// MFMA GEMM tile: C[gm0+128, gn0+BN] (+)= A @ Bt^T, fp32 out.
// A row-major [M][ldK] bf16; Bt row-major [N][ldK] bf16 (i.e. B transposed).
// BK=32; 4 waves (2x2); wave tile 64 x BN/2; 16x16x32 MFMA.
// LDS rows 64B, XOR-swizzled 16B slots: slot = koct ^ ((row>>1)&3) -> 2-way.
// Reg-staged double buffer, one barrier per K-step.
// ---------------------------------------------------------------------------
template <int BN, bool TWOPASS>
__device__ __forceinline__ void gemm_mfma_tile(
    const u16* __restrict__ A0, const u16* __restrict__ A1,
    const u16* __restrict__ Bt, float* __restrict__ C,
    const float* __restrict__ bias, int ldK, int nk1,
    int gm0, int gn0, char* lds)
{
    constexpr int FN    = BN / 32;
    constexpr int WNw   = BN / 2;
    constexpr int BR    = BN / 64;            // B staging rounds
    constexpr int BUFSZ = 8192 + BN * 64;

    const int tid  = threadIdx.x;
    const int wave = tid >> 6, l = tid & 63, ml = l & 15, koct = l >> 4;
    const int wm = wave >> 1, wn = wave & 1;
    const int swz = koct ^ ((ml >> 1) & 3);
    const int a_ro = (wm * 64 + ml) * 64 + swz * 16;
    const int b_ro = (wn * WNw + ml) * 64 + swz * 16;

    const int sm = tid >> 2, sq = tid & 3;
    int wAo[2], wBo[BR];
    size_t gAo[2], gBo[BR];
#pragma unroll
    for (int q = 0; q < 2; ++q) {
        const int m = q * 64 + sm;
        wAo[q] = m * 64 + ((sq ^ ((m >> 1) & 3)) * 16);
        gAo[q] = (size_t)(gm0 + m) * ldK * 2 + sq * 16;
    }
#pragma unroll
    for (int q = 0; q < BR; ++q) {
        const int n = q * 64 + sm;
        wBo[q] = n * 64 + ((sq ^ ((n >> 1) & 3)) * 16);
        gBo[q] = (size_t)(gn0 + n) * ldK * 2 + sq * 16;
    }

    f32x4 acc[4][FN];
    const f32x4 zz = {0.f, 0.f, 0.f, 0.f};
#pragma unroll
    for (int i = 0; i < 4; ++i)
#pragma unroll
        for (int j = 0; j < FN; ++j) acc[i][j] = zz;

    const char* A0c = (const char*)A0;
    const char* A1c = (const char*)A1;
    const char* Btc = (const char*)Bt;
    const int NKT = TWOPASS ? 2 * nk1 : nk1;

    uint4 st[2 + BR];

    auto stage = [&](int kt) {
        const bool second = TWOPASS && (kt >= nk1);
        const int ktm = second ? kt - nk1 : kt;
        const char* Ab = second ? A1c : A0c;
        const size_t koff = (size_t)ktm * 64;
        st[0] = *(const uint4*)(Ab + gAo[0] + koff);
        st[1] = *(const uint4*)(Ab + gAo[1] + koff);
#pragma unroll
        for (int q = 0; q < BR; ++q)
            st[2 + q] = *(const uint4*)(Btc + gBo[q] + koff);
    };
    auto dswrite = [&](int buf) {
        char* d = lds + buf * BUFSZ;
        *(uint4*)(d + wAo[0]) = st[0];
        *(uint4*)(d + wAo[1]) = st[1];
#pragma unroll
        for (int q = 0; q < BR; ++q)
            *(uint4*)(d + 8192 + wBo[q]) = st[2 + q];
    };
    auto compute = [&](int buf) {
        const char* As = lds + buf * BUFSZ;
        const char* Bs = As + 8192;
        bf16x8 af[4], bfv[FN];
#pragma unroll
        for (int fm = 0; fm < 4; ++fm)
            af[fm] = *(const bf16x8*)(As + a_ro + fm * 1024);
#pragma unroll
        for (int fn = 0; fn < FN; ++fn)
            bfv[fn] = *(const bf16x8*)(Bs + b_ro + fn * 1024);
#pragma unroll
        for (int fm = 0; fm < 4; ++fm)
#pragma unroll
            for (int fn = 0; fn < FN; ++fn)
                acc[fm][fn] = __builtin_amdgcn_mfma_f32_16x16x32_bf16(
                    af[fm], bfv[fn], acc[fm][fn], 0, 0, 0);
    };

    stage(0); dswrite(0); __syncthreads();
    for (int kt = 0; kt < NKT; ++kt) {
        if (kt + 1 < NKT) stage(kt + 1);
        compute(kt & 1);
        if (kt + 1 < NKT) dswrite((kt + 1) & 1);
        __syncthreads();
    }

    float br[FN];
#pragma unroll
    for (int fn = 0; fn < FN; ++fn)
        br[fn] = bias ? bias[gn0 + wn * WNw + fn * 16 + ml] : 0.f;
#pragma unroll
    for (int fm = 0; fm < 4; ++fm) {
        const int rowb = gm0 + wm * 64 + fm * 16 + koct * 4;
#pragma unroll
        for (int fn = 0; fn < FN; ++fn) {
            const int col = gn0 + wn * WNw + fn * 16 + ml;
#pragma unroll
            for (int r = 0; r < 4; ++r)
                C[(size_t)(rowb + r) * 1024 + col] = acc[fm][fn][r] + br[fn];
        }
    }
}

// kernelA: [0,192) GEMM1 split-K3 (chunk c, in-block hi+lo passes) -> p_h1[c]
//          [192,256) Wc = oW2 @ eW1' (in-block hi+lo)              -> p_wc
__global__ __launch_bounds__(256) void kernelA_mfma(
    const u16* __restrict__ oh, const u16* __restrict__ ol,
    const u16* __restrict__ bW1t, const u16* __restrict__ o2h,
    const u16* __restrict__ o2l, const u16* __restrict__ bE1t,
    float* __restrict__ p_h1, float* __restrict__ p_wc)
{
    __shared__ alignas(16) char lds[2 * 16384];
    const int bid = blockIdx.x;
    if (bid < 192) {
        const int c = bid >> 6, tile = bid & 63;
        gemm_mfma_tile<128, true>(oh + c * 1024, ol + c * 1024, bW1t + c * 1024,
                                  p_h1 + (size_t)c * 1048576, nullptr,
                                  3072, 32, (tile >> 3) * 128, (tile & 7) * 128,
                                  lds);
    } else {
        const int tile = bid - 192;
        gemm_mfma_tile<128, true>(o2h, o2l, bE1t, p_wc, nullptr,
                                  1024, 32, (tile >> 3) * 128, (tile & 7) * 128,
                                  lds);
    }
}

// epilogueK: [0,256) h1 = relu(p0+p1+p2+ob1) -> h1h/h1l bf16 split
//            [256,512) Wct[n][k] = bf16(p_wc[k][n])  (transpose)
//            [512,516) biasWc[n] = eb1[n] + sum_k ob2[k]*eW1[20+k][n]
__global__ __launch_bounds__(256) void epilogueK(
    const float* __restrict__ p_h1, const float* __restrict__ p_wc,
    const float* __restrict__ ob1, const float* __restrict__ ob2,
    const float* __restrict__ eW1, const float* __restrict__ eb1,
    u16* __restrict__ h1h, u16* __restrict__ h1l, u16* __restrict__ Wct,
    float* __restrict__ biasWc)
{
    __shared__ float tl[64][65];
    const int bid = blockIdx.x, t = threadIdx.x;
    if (bid < 256) {
#pragma unroll
        for (int it = 0; it < 4; ++it) {
            const int g = bid * 1024 + it * 256 + t;
            const size_t e = (size_t)g * 4;
            float4 a = *(const float4*)(p_h1 + e);
            float4 b = *(const float4*)(p_h1 + 1048576 + e);
            float4 c = *(const float4*)(p_h1 + 2097152 + e);
            float4 s = *(const float4*)(ob1 + ((g * 4) & 1023));
            const float *ap = (const float*)&a, *bp = (const float*)&b,
                        *cp = (const float*)&c, *sp = (const float*)&s;
            ushort4 uh, ul;
            u16 H[4], L[4];
#pragma unroll
            for (int j = 0; j < 4; ++j) {
                const float v = fmaxf(ap[j] + bp[j] + cp[j] + sp[j], 0.f);
                H[j] = f2bf(v);
                L[j] = f2bf(v - bf2f(H[j]));
            }
            uh.x = H[0]; uh.y = H[1]; uh.z = H[2]; uh.w = H[3];
            ul.x = L[0]; ul.y = L[1]; ul.z = L[2]; ul.w = L[3];
            *(ushort4*)(h1h + e) = uh;
            *(ushort4*)(h1l + e) = ul;
        }
    } else if (bid < 512) {
        const int idx = bid - 256;
        const int k0 = (idx >> 4) * 64, n0 = (idx & 15) * 64;
#pragma unroll
        for (int r = 0; r < 4; ++r) {
            const int k = k0 + r * 16 + (t >> 4);
            float4 v = *(const float4*)(p_wc + (size_t)k * 1024 + n0 + (t & 15) * 4);
            const float* vp = (const float*)&v;
#pragma unroll
            for (int j = 0; j < 4; ++j)
                tl[r * 16 + (t >> 4)][(t & 15) * 4 + j] = vp[j];
        }
        __syncthreads();
#pragma unroll
        for (int r = 0; r < 4; ++r) {
            const int n = r * 16 + (t >> 4);
            ushort4 u;
            u.x = f2bf(tl[(t & 15) * 4 + 0][n]);
            u.y = f2bf(tl[(t & 15) * 4 + 1][n]);
            u.z = f2bf(tl[(t & 15) * 4 + 2][n]);
            u.w = f2bf(tl[(t & 15) * 4 + 3][n]);
            *(ushort4*)(Wct + (size_t)(n0 + n) * 1024 + k0 + (t & 15) * 4) = u;
        }
    } else {
        const int n = (bid - 512) * 256 + t;
        float s = eb1[n];
        for (int k = 0; k < 1024; ++k)
            s = fmaf(ob2[k], eW1[(size_t)(DIN + k) * H_ + n], s);
        biasWc[n] = s;
    }
}

// kernelB: base0 = h1h @ Wc ; base1 = h1l @ Wc + biasWc   (BN=64, 256 blocks)
__global__ __launch_bounds__(256) void kernelB_mfma(
    const u16* __restrict__ h1h, const u16* __restrict__ h1l,
    const u16* __restrict__ Wct, const float* __restrict__ biasWc,
    float* __restrict__ base0, float* __restrict__ base1)
{
    __shared__ alignas(16) char lds[2 * 12288];
    const int bid = blockIdx.x;
    const int p = bid >> 7, tile = bid & 127;
    gemm_mfma_tile<64, false>(p ? h1l : h1h, nullptr, Wct,
                              p ? base1 : base0, p ? biasWc : nullptr,
                              1024, 32, (tile >> 4) * 128, (tile & 15) * 64,
                              lds);
}

// ===========================================================================
// Fused sequential expert kernel (fp32, unchanged).
// ===========================================================================
__global__ __launch_bounds__(256, 2) void expert_seq(
    const float* __restrict__ x, const float* __restrict__ eW1,
    const float* __restrict__ eW2, const float* __restrict__ eb2,
    const float* __restrict__ base0, const float* __restrict__ base1,
    float* __restrict__ out)
{
    const int b   = blockIdx.x;
    const int tid = threadIdx.x;
    const int j0  = tid * 4;

    __shared__ float xl[T_ * DIN];
    __shared__ float pl[256 * 29];
    __shared__ float pl2[256];
    __shared__ float prevs;

    for (int idx = tid; idx < T_ * DIN; idx += 256)
        xl[idx] = x[(size_t)b * (T_ * DIN) + idx];

    float w1r[DIN][4];
#pragma unroll
    for (int d = 0; d < DIN; ++d)
        *(float4*)w1r[d] = *(const float4*)&eW1[(size_t)d * H_ + j0];

    float base_r[4];
    *(float4*)base_r = *(const float4*)&base0[(size_t)b * H_ + j0];
    if (base1) {
        float4 b1 = *(const float4*)&base1[(size_t)b * H_ + j0];
        base_r[0] += b1.x; base_r[1] += b1.y;
        base_r[2] += b1.z; base_r[3] += b1.w;
    }

    float w2r[4][C_];
#pragma unroll
    for (int i = 0; i < 4; ++i)
#pragma unroll
        for (int c = 0; c < C_; ++c)
            w2r[i][c] = eW2[(size_t)(j0 + i) * C_ + c];

    const float myb = (tid < C_) ? eb2[tid] : 0.f;
    __syncthreads();

    float prev = 0.f;
#pragma unroll 1
    for (int t = 0; t < TOUT; ++t) {
        const float cur0 = (t == 0) ? xl[0] : prev;

        float h[4];
#pragma unroll
        for (int i = 0; i < 4; ++i)
            h[i] = fmaf(cur0, w1r[0][i], base_r[i]);
#pragma unroll
        for (int d = 1; d < DIN; ++d) {
            const float xv = xl[t * DIN + d];
#pragma unroll
            for (int i = 0; i < 4; ++i)
                h[i] = fmaf(xv, w1r[d][i], h[i]);
        }
#pragma unroll
        for (int i = 0; i < 4; ++i)
            h[i] = fmaxf(h[i], 0.f);

        float p[C_];
#pragma unroll
        for (int c = 0; c < C_; ++c)
            p[c] = h[0] * w2r[0][c];
#pragma unroll
        for (int i = 1; i < 4; ++i)
#pragma unroll
            for (int c = 0; c < C_; ++c)
                p[c] = fmaf(h[i], w2r[i][c], p[c]);

#pragma unroll
        for (int c = 0; c < C_; ++c)
            pl[tid * 29 + c] = p[c];
        __syncthreads();

        {
            const int c2 = tid & 31, grp = tid >> 5;
            float s = 0.f;
            if (c2 < C_) {
                const int basei = grp * 32 * 29 + c2;
#pragma unroll
                for (int s2 = 0; s2 < 32; ++s2)
                    s += pl[basei + s2 * 29];
            }
            pl2[tid] = s;
        }
        __syncthreads();

        if (tid < C_) {
            float o = myb;
#pragma unroll
            for (int g = 0; g < 8; ++g)
                o += pl2[g * 32 + tid];
            out[((size_t)b * TOUT + t) * C_ + tid] = o;
            if (tid == 0) prevs = o;
        }
        __syncthreads();
        prev = prevs;
    }
}

// ===========================================================================
// FALLBACK fp32 path (round-2 kernels) — used if ws is too small.
// ===========================================================================
struct GemmSmem {
    float As[2][16][68];
    float Bs[2][16][64];
};

template <int RELU>
__device__ __forceinline__ void gemm_core(
    const float* __restrict__ A, int lda,
    const float* __restrict__ Bm, int ldb,
    const float* __restrict__ bias, const float* __restrict__ bias_parts,
    float* __restrict__ Cc, int ldc, int K, int tile, GemmSmem& sm)
{
    const int tid = threadIdx.x;
    const int bm = (tile >> 4) * 64, bn = (tile & 15) * 64;
    const int wave = tid >> 6, l = tid & 63;
    const int n0 = (wave & 1) * 32 + (l & 7) * 4;
    const int m0 = (wave >> 1) * 32 + (l >> 3) * 4;
    const int am = tid >> 2, akq = tid & 3;
    const int bk = tid >> 4, bnq = tid & 15;
    const float* Arow = A + (size_t)(bm + am) * lda + akq * 4;
    const float* Brow = Bm + (size_t)bk * ldb + bn + bnq * 4;
    float acc[4][4] = {};
    const int nIter = (K + 15) >> 4;
    {
        const int ak = akq * 4;
        float4 av = (ak + 4 <= K) ? *(const float4*)(Arow)
                                  : make_float4(0.f, 0.f, 0.f, 0.f);
        float4 bv = (bk < K) ? *(const float4*)(Brow)
                             : make_float4(0.f, 0.f, 0.f, 0.f);
        sm.As[0][akq * 4 + 0][am] = av.x; sm.As[0][akq * 4 + 1][am] = av.y;
        sm.As[0][akq * 4 + 2][am] = av.z; sm.As[0][akq * 4 + 3][am] = av.w;
        *(float4*)&sm.Bs[0][bk][bnq * 4] = bv;
    }
    __syncthreads();
    for (int it = 0; it < nIter; ++it) {
        const int cur = it & 1;
        const bool pf = (it + 1 < nIter);
        float4 pav, pbv;
        if (pf) {
            const int k0 = (it + 1) << 4, ak = k0 + akq * 4;
            pav = (ak + 4 <= K) ? *(const float4*)(Arow + k0)
                                : make_float4(0.f, 0.f, 0.f, 0.f);
            pbv = (k0 + bk < K) ? *(const float4*)(Brow + (size_t)k0 * ldb)
                                : make_float4(0.f, 0.f, 0.f, 0.f);
        }
#pragma unroll
        for (int kk = 0; kk < 16; ++kk) {
            float ar[4], br[4];
            *(float4*)ar = *(const float4*)&sm.As[cur][kk][m0];
            *(float4*)br = *(const float4*)&sm.Bs[cur][kk][n0];
#pragma unroll
            for (int r = 0; r < 4; ++r)
#pragma unroll
                for (int c = 0; c < 4; ++c)
                    acc[r][c] = fmaf(ar[r], br[c], acc[r][c]);
        }
        if (pf) {
            const int nb = cur ^ 1;
            sm.As[nb][akq * 4 + 0][am] = pav.x; sm.As[nb][akq * 4 + 1][am] = pav.y;
            sm.As[nb][akq * 4 + 2][am] = pav.z; sm.As[nb][akq * 4 + 3][am] = pav.w;
            *(float4*)&sm.Bs[nb][bk][bnq * 4] = pbv;
        }
        __syncthreads();
    }
    float bias4[4];
#pragma unroll
    for (int c = 0; c < 4; ++c) {
        const int col = bn + n0 + c;
        float b = bias ? bias[col] : 0.f;
        if (bias_parts)
#pragma unroll
            for (int p = 0; p < 8; ++p) b += bias_parts[p * H_ + col];
        bias4[c] = b;
    }
#pragma unroll
    for (int r = 0; r < 4; ++r) {
        float4 v; float* vp = (float*)&v;
#pragma unroll
        for (int c = 0; c < 4; ++c) {
            float t2 = acc[r][c] + bias4[c];
            if (RELU) t2 = fmaxf(t2, 0.f);
            vp[c] = t2;
        }
        *(float4*)&Cc[(size_t)(bm + m0 + r) * ldc + bn + n0] = v;
    }
}

__global__ __launch_bounds__(256) void kernelA_fb(
    const float* __restrict__ o, const float* __restrict__ oW1,
    const float* __restrict__ ob1, const float* __restrict__ oW2,
    const float* __restrict__ eW1, const float* __restrict__ ob2,
    float* __restrict__ h1, float* __restrict__ Wc, float* __restrict__ biasc)
{
    __shared__ GemmSmem sm;
    const int bid = blockIdx.x;
    if (bid < 256) {
        gemm_core<1>(o, OBJ_, oW1, H_, ob1, nullptr, h1, H_, OBJ_, bid, sm);
    } else if (bid < 512) {
        gemm_core<0>(oW2, H_, eW1 + (size_t)DIN * H_, H_, nullptr, nullptr,
                     Wc, H_, H_, bid - 256, sm);
    } else {
        const int r = bid - 512, kc = r >> 2, nb = r & 3;
        const int n = nb * 256 + (int)threadIdx.x;
        const int k0 = kc * 128;
        float acc = 0.f;
#pragma unroll 8
        for (int k = 0; k < 128; ++k)
            acc = fmaf(ob2[k0 + k], eW1[(size_t)(DIN + k0 + k) * H_ + n], acc);
        biasc[kc * H_ + n] = acc;
    }
}

__global__ __launch_bounds__(256) void kernelB_fb(
    const float* __restrict__ h1, const float* __restrict__ Wc,
    const float* __restrict__ eb1, const float* __restrict__ biasc,
    float* __restrict__ base0)
{
    __shared__ GemmSmem sm;
    gemm_core<0>(h1, H_, Wc, H_, eb1, biasc, base0, H_, H_, blockIdx.x, sm);
}

// ===========================================================================
extern "C" void kernel_launch(void* const* d_in, const int* in_sizes, int n_in,
                              void* d_out, int out_size, void* d_ws, size_t ws_size,
                              hipStream_t stream)
{
    const float* o   = (const float*)d_in[0];
    const float* x   = (const float*)d_in[1];
    const float* oW1 = (const float*)d_in[2];
    const float* ob1 = (const float*)d_in[3];
    const float* oW2 = (const float*)d_in[4];
    const float* ob2 = (const float*)d_in[5];
    const float* eW1 = (const float*)d_in[6];
    const float* eb1 = (const float*)d_in[7];
    const float* eW2 = (const float*)d_in[8];
    const float* eb2 = (const float*)d_in[9];

    float* outp = (float*)d_out;
    float* ws   = (float*)d_ws;
    dim3 blk(256);

    const size_t NEED = 41947136;  // bytes for MFMA plan
    if (ws_size >= NEED) {
        // ---- MFMA path ----
        float* p_h1   = ws;                     // 3M f (later base0/base1)
        float* p_wc   = ws + 3145728;           // 1M f
        float* biasWc = ws + 4194304;           // 1K f (+pad)
        u16*   ub     = (u16*)(ws + 4195328);
        u16 *oh = ub,            *ol = ub + 3145728, *bW1t = ub + 6291456;
        u16 *o2h = ub + 9437184, *o2l = ub + 10485760, *bE1t = ub + 11534336;
        u16 *h1h = oh, *h1l = oh + 1048576, *Wct = oh + 2097152;  // reuse oh
        float* base0 = p_h1;             // reuse p_h1 region
        float* base1 = p_h1 + 1048576;

        convertK<<<dim3(1664), blk, 0, stream>>>(o, oW1, eW1, oW2,
                                                 oh, ol, bW1t, bE1t, o2h, o2l);
        kernelA_mfma<<<dim3(256), blk, 0, stream>>>(oh, ol, bW1t, o2h, o2l,
                                                    bE1t, p_h1, p_wc);
        epilogueK<<<dim3(516), blk, 0, stream>>>(p_h1, p_wc, ob1, ob2, eW1,
                                                 eb1, h1h, h1l, Wct, biasWc);
        kernelB_mfma<<<dim3(256), blk, 0, stream>>>(h1h, h1l, Wct, biasWc,
                                                    base0, base1);
        expert_seq<<<dim3(B_), blk, 0, stream>>>(x, eW1, eW2, eb2,
                                                 base0, base1, outp);
    } else {
        // ---- fp32 fallback (round-2 path) ----
        const size_t MF = (size_t)H_ * H_;
        float* h1    = ws;
        float* Wc    = ws + MF;
        float* base0 = ws + 2 * MF;
        float* biasc = outp;  // staged in d_out head, overwritten by expert

        kernelA_fb<<<dim3(544), blk, 0, stream>>>(o, oW1, ob1, oW2, eW1, ob2,
                                                  h1, Wc, biasc);
        kernelB_fb<<<dim3(256), blk, 0, stream>>>(h1, Wc, eb1, biasc, base0);
        expert_seq<<<dim3(B_), blk, 0, stream>>>(x, eW1, eW2, eb2,
                                                 base0, nullptr, outp);
    }
}

// Round 4
// 241.163 us; speedup vs baseline: 2.3649x; 1.3226x over previous
//
#include <hip/hip_runtime.h>
#include <hip/hip_bf16.h>

#define B_   1024
#define T_   85
#define DIN  20
#define H_   1024
#define C_   27
#define OBJ_ (T_ * 36)   // 3060
#define TOUT (T_ - 1)    // 84

typedef unsigned short u16;
typedef __attribute__((ext_vector_type(8))) short bf16x8;
typedef __attribute__((ext_vector_type(4))) float f32x4;

__device__ __forceinline__ u16 f2bf(float f) {
    __hip_bfloat16 h = __float2bfloat16(f);
    return *reinterpret_cast<u16*>(&h);
}
__device__ __forceinline__ float bf2f(u16 u) {
    __hip_bfloat16 h;
    *reinterpret_cast<u16*>(&h) = u;
    return __bfloat162float(h);
}

// ===========================================================================
// convertK2: all input conversions in one launch.
//  [0,512)     o [1024][3060] f32 -> o_bf [1024][3072] bf16 (pad 0)
//  [512,1280)  oW1 [3060][1024] -> bW1t [1024 n][3072 k] bf16 (transpose)
//  [1280,1536) eW1[20:] [1024][1024] -> bE1t [1024][1024] bf16 (transpose)
//  [1536,1664) oW2 -> o2bf bf16
//  [1664,1696) eW2 [1024][27] -> w2th/w2tl [32][1024] (transpose, hi/lo split)
//  [1696,1700) eW1[0:20] -> e1t20 [1024 n][32 k] bf16 (transpose, pad 0)
//  [1700,1704) biasWc[n] = eb1[n] + sum_k ob2[k]*eW1[20+k][n]
// ===========================================================================
__global__ __launch_bounds__(256) void convertK2(
    const float* __restrict__ o, const float* __restrict__ oW1,
    const float* __restrict__ eW1, const float* __restrict__ oW2,
    const float* __restrict__ eW2, const float* __restrict__ ob2,
    const float* __restrict__ eb1,
    u16* __restrict__ o_bf, u16* __restrict__ bW1t, u16* __restrict__ bE1t,
    u16* __restrict__ o2bf, u16* __restrict__ w2th, u16* __restrict__ w2tl,
    u16* __restrict__ e1t20, float* __restrict__ biasWc)
{
    __shared__ float tl[64][65];
    const int bid = blockIdx.x, t = threadIdx.x;

    if (bid < 512) {
        for (int it = 0; it < 6; ++it) {
            const int idx = (bid * 256 + t) + it * 131072;
            const int row = idx / 768, g = idx - row * 768;
            float4 v = make_float4(0.f, 0.f, 0.f, 0.f);
            if (g < 765) v = *(const float4*)(o + (size_t)row * 3060 + g * 4);
            const float* vp = (const float*)&v;
            ushort4 uh;
            uh.x = f2bf(vp[0]); uh.y = f2bf(vp[1]);
            uh.z = f2bf(vp[2]); uh.w = f2bf(vp[3]);
            *(ushort4*)(o_bf + (size_t)row * 3072 + g * 4) = uh;
        }
    } else if (bid < 1536) {
        const bool isW1 = (bid < 1280);
        const int idx = isW1 ? (bid - 512) : (bid - 1280);
        const int k0 = (idx >> 4) * 64, n0 = (idx & 15) * 64;
        const float* src = isW1 ? oW1 : (eW1 + (size_t)DIN * H_);
        const int Ksrc = isW1 ? 3060 : 1024;
        u16* dst = isW1 ? bW1t : bE1t;
        const int ldk = isW1 ? 3072 : 1024;
#pragma unroll
        for (int r = 0; r < 4; ++r) {
            const int k = k0 + r * 16 + (t >> 4);
            float4 v = make_float4(0.f, 0.f, 0.f, 0.f);
            if (k < Ksrc)
                v = *(const float4*)(src + (size_t)k * 1024 + n0 + (t & 15) * 4);
            const float* vp = (const float*)&v;
#pragma unroll
            for (int j = 0; j < 4; ++j)
                tl[r * 16 + (t >> 4)][(t & 15) * 4 + j] = vp[j];
        }
        __syncthreads();
#pragma unroll
        for (int r = 0; r < 4; ++r) {
            const int n = r * 16 + (t >> 4);
            ushort4 u;
            u.x = f2bf(tl[(t & 15) * 4 + 0][n]);
            u.y = f2bf(tl[(t & 15) * 4 + 1][n]);
            u.z = f2bf(tl[(t & 15) * 4 + 2][n]);
            u.w = f2bf(tl[(t & 15) * 4 + 3][n]);
            *(ushort4*)(dst + (size_t)(n0 + n) * ldk + k0 + (t & 15) * 4) = u;
        }
    } else if (bid < 1664) {
        const int base = (bid - 1536) * 256 + t;
#pragma unroll
        for (int it = 0; it < 8; ++it) {
            const int g = base + it * 32768;
            float4 v = *(const float4*)(oW2 + (size_t)g * 4);
            const float* vp = (const float*)&v;
            ushort4 uh;
            uh.x = f2bf(vp[0]); uh.y = f2bf(vp[1]);
            uh.z = f2bf(vp[2]); uh.w = f2bf(vp[3]);
            *(ushort4*)(o2bf + (size_t)g * 4) = uh;
        }
    } else if (bid < 1696) {
        const int c = bid - 1664;
#pragma unroll
        for (int kk = 0; kk < 4; ++kk) {
            const int k = kk * 256 + t;
            const float v = (c < C_) ? eW2[(size_t)k * C_ + c] : 0.f;
            const u16 hh = f2bf(v);
            w2th[(size_t)c * 1024 + k] = hh;
            w2tl[(size_t)c * 1024 + k] = f2bf(v - bf2f(hh));
        }
    } else if (bid < 1700) {
        const int n = (bid - 1696) * 256 + t;
        u16 buf[32];
#pragma unroll
        for (int k = 0; k < 32; ++k)
            buf[k] = (k < DIN) ? f2bf(eW1[(size_t)k * H_ + n]) : (u16)0;
#pragma unroll
        for (int q = 0; q < 4; ++q)
            *(uint4*)(e1t20 + (size_t)n * 32 + q * 8) = *(uint4*)&buf[q * 8];
    } else {
        const int n = (bid - 1700) * 256 + t;
        float s = eb1[n];
        for (int k = 0; k < 1024; ++k)
            s = fmaf(ob2[k], eW1[(size_t)(DIN + k) * H_ + n], s);
        biasWc[n] = s;
    }
}

// ---------------------------------------------------------------------------
// MFMA GEMM tile (single bf16 A): C[gm0+128, gn0+64] = A @ Bt^T (+bias).
// ---------------------------------------------------------------------------
template <int BN>
__device__ __forceinline__ void gemm_mfma_tile(
    const u16* __restrict__ A0, const u16* __restrict__ Bt,
    float* __restrict__ C, const float* __restrict__ bias,
    int ldK, int nk1, int gm0, int gn0, char* lds)
{
    constexpr int FN    = BN / 32;
    constexpr int WNw   = BN / 2;
    constexpr int BR    = BN / 64;
    constexpr int BUFSZ = 8192 + BN * 64;

    const int tid  = threadIdx.x;
    const int wave = tid >> 6, l = tid & 63, ml = l & 15, koct = l >> 4;
    const int wm = wave >> 1, wn = wave & 1;
    const int swz = koct ^ ((ml >> 1) & 3);
    const int a_ro = (wm * 64 + ml) * 64 + swz * 16;
    const int b_ro = (wn * WNw + ml) * 64 + swz * 16;

    const int sm = tid >> 2, sq = tid & 3;
    int wAo[2], wBo[BR];
    size_t gAo[2], gBo[BR];
#pragma unroll
    for (int q = 0; q < 2; ++q) {
        const int m = q * 64 + sm;
        wAo[q] = m * 64 + ((sq ^ ((m >> 1) & 3)) * 16);
        gAo[q] = (size_t)(gm0 + m) * ldK * 2 + sq * 16;
    }
#pragma unroll
    for (int q = 0; q < BR; ++q) {
        const int n = q * 64 + sm;
        wBo[q] = n * 64 + ((sq ^ ((n >> 1) & 3)) * 16);
        gBo[q] = (size_t)(gn0 + n) * ldK * 2 + sq * 16;
    }

    f32x4 acc[4][FN];
    const f32x4 zz = {0.f, 0.f, 0.f, 0.f};
#pragma unroll
    for (int i = 0; i < 4; ++i)
#pragma unroll
        for (int j = 0; j < FN; ++j) acc[i][j] = zz;

    const char* A0c = (const char*)A0;
    const char* Btc = (const char*)Bt;

    uint4 st[2 + BR];
    auto stage = [&](int kt) {
        const size_t koff = (size_t)kt * 64;
        st[0] = *(const uint4*)(A0c + gAo[0] + koff);
        st[1] = *(const uint4*)(A0c + gAo[1] + koff);
#pragma unroll
        for (int q = 0; q < BR; ++q)
            st[2 + q] = *(const uint4*)(Btc + gBo[q] + koff);
    };
    auto dswrite = [&](int buf) {
        char* d = lds + buf * BUFSZ;
        *(uint4*)(d + wAo[0]) = st[0];
        *(uint4*)(d + wAo[1]) = st[1];
#pragma unroll
        for (int q = 0; q < BR; ++q)
            *(uint4*)(d + 8192 + wBo[q]) = st[2 + q];
    };
    auto compute = [&](int buf) {
        const char* As = lds + buf * BUFSZ;
        const char* Bs = As + 8192;
        bf16x8 af[4], bfv[FN];
#pragma unroll
        for (int fm = 0; fm < 4; ++fm)
            af[fm] = *(const bf16x8*)(As + a_ro + fm * 1024);
#pragma unroll
        for (int fn = 0; fn < FN; ++fn)
            bfv[fn] = *(const bf16x8*)(Bs + b_ro + fn * 1024);
#pragma unroll
        for (int fm = 0; fm < 4; ++fm)
#pragma unroll
            for (int fn = 0; fn < FN; ++fn)
                acc[fm][fn] = __builtin_amdgcn_mfma_f32_16x16x32_bf16(
                    af[fm], bfv[fn], acc[fm][fn], 0, 0, 0);
    };

    stage(0); dswrite(0); __syncthreads();
    for (int kt = 0; kt < nk1; ++kt) {
        if (kt + 1 < nk1) stage(kt + 1);
        compute(kt & 1);
        if (kt + 1 < nk1) dswrite((kt + 1) & 1);
        __syncthreads();
    }

    float br[FN];
#pragma unroll
    for (int fn = 0; fn < FN; ++fn)
        br[fn] = bias ? bias[gn0 + wn * WNw + fn * 16 + ml] : 0.f;
#pragma unroll
    for (int fm = 0; fm < 4; ++fm) {
        const int rowb = gm0 + wm * 64 + fm * 16 + koct * 4;
#pragma unroll
        for (int fn = 0; fn < FN; ++fn) {
            const int col = gn0 + wn * WNw + fn * 16 + ml;
#pragma unroll
            for (int r = 0; r < 4; ++r)
                C[(size_t)(rowb + r) * 1024 + col] = acc[fm][fn][r] + br[fn];
        }
    }
}

// kernelA2: [0,384) GEMM1 split-K3 (3 x 128 tiles of 128x64) -> p_h1[c]
//           [384,512) Wc = o2bf @ bE1t -> p_wc
__global__ __launch_bounds__(256) void kernelA2(
    const u16* __restrict__ o_bf, const u16* __restrict__ bW1t,
    const u16* __restrict__ o2bf, const u16* __restrict__ bE1t,
    float* __restrict__ p_h1, float* __restrict__ p_wc)
{
    __shared__ alignas(16) char lds[2 * 12288];
    const int bid = blockIdx.x;
    if (bid < 384) {
        const int c = bid >> 7, tl = bid & 127;
        gemm_mfma_tile<64>(o_bf + c * 1024, bW1t + c * 1024,
                           p_h1 + (size_t)c * 1048576, nullptr, 3072, 32,
                           (tl >> 4) * 128, (tl & 15) * 64, lds);
    } else {
        const int tl = bid - 384;
        gemm_mfma_tile<64>(o2bf, bE1t, p_wc, nullptr, 1024, 32,
                           (tl >> 4) * 128, (tl & 15) * 64, lds);
    }
}

// epilogue2: [0,256) h1bf = bf16(relu(p0+p1+p2+ob1)); [256,512) Wct = bf16(p_wc^T)
__global__ __launch_bounds__(256) void epilogue2(
    const float* __restrict__ p_h1, const float* __restrict__ p_wc,
    const float* __restrict__ ob1,
    u16* __restrict__ h1bf, u16* __restrict__ Wct)
{
    __shared__ float tl[64][65];
    const int bid = blockIdx.x, t = threadIdx.x;
    if (bid < 256) {
#pragma unroll
        for (int it = 0; it < 4; ++it) {
            const int g = bid * 1024 + it * 256 + t;
            const size_t e = (size_t)g * 4;
            float4 a = *(const float4*)(p_h1 + e);
            float4 b = *(const float4*)(p_h1 + 1048576 + e);
            float4 c = *(const float4*)(p_h1 + 2097152 + e);
            float4 s = *(const float4*)(ob1 + (e & 1023));
            const float *ap = (const float*)&a, *bp = (const float*)&b,
                        *cp = (const float*)&c, *sp = (const float*)&s;
            ushort4 uh;
            u16* up = (u16*)&uh;
#pragma unroll
            for (int j = 0; j < 4; ++j)
                up[j] = f2bf(fmaxf(ap[j] + bp[j] + cp[j] + sp[j], 0.f));
            *(ushort4*)(h1bf + e) = uh;
        }
    } else {
        const int idx = bid - 256;
        const int k0 = (idx >> 4) * 64, n0 = (idx & 15) * 64;
#pragma unroll
        for (int r = 0; r < 4; ++r) {
            const int k = k0 + r * 16 + (t >> 4);
            float4 v = *(const float4*)(p_wc + (size_t)k * 1024 + n0 + (t & 15) * 4);
            const float* vp = (const float*)&v;
#pragma unroll
            for (int j = 0; j < 4; ++j)
                tl[r * 16 + (t >> 4)][(t & 15) * 4 + j] = vp[j];
        }
        __syncthreads();
#pragma unroll
        for (int r = 0; r < 4; ++r) {
            const int n = r * 16 + (t >> 4);
            ushort4 u;
            u.x = f2bf(tl[(t & 15) * 4 + 0][n]);
            u.y = f2bf(tl[(t & 15) * 4 + 1][n]);
            u.z = f2bf(tl[(t & 15) * 4 + 2][n]);
            u.w = f2bf(tl[(t & 15) * 4 + 3][n]);
            *(ushort4*)(Wct + (size_t)(n0 + n) * 1024 + k0 + (t & 15) * 4) = u;
        }
    }
}

// kernelB2: base = h1bf @ Wct^T + biasWc  (128 blocks of 128x64)
__global__ __launch_bounds__(256) void kernelB2(
    const u16* __restrict__ h1bf, const u16* __restrict__ Wct,
    const float* __restrict__ biasWc, float* __restrict__ base)
{
    __shared__ alignas(16) char lds[2 * 12288];
    const int bid = blockIdx.x;
    gemm_mfma_tile<64>(h1bf, Wct, base, biasWc, 1024, 32,
                       (bid >> 4) * 128, (bid & 15) * 64, lds);
}

// ===========================================================================
// Phase 1: sequential chain, channel 0 only. One block per batch row.
// Emits cur0_buf[b][t] = channel-0 input of step t (t=0..83).
// ===========================================================================
__global__ __launch_bounds__(256, 4) void chain_seq(
    const float* __restrict__ x, const float* __restrict__ eW1,
    const float* __restrict__ eW2, const float* __restrict__ eb2,
    const float* __restrict__ base, float* __restrict__ cur0_buf)
{
    const int b = blockIdx.x, tid = threadIdx.x;
    const int j0 = tid * 4;
    const int wid = tid >> 6, lane = tid & 63;

    __shared__ float xl[T_ * DIN];
    __shared__ float plw[2][4];

    for (int i = tid; i < T_ * DIN; i += 256)
        xl[i] = x[(size_t)b * (T_ * DIN) + i];

    float w1r[DIN][4];
#pragma unroll
    for (int d = 0; d < DIN; ++d)
        *(float4*)w1r[d] = *(const float4*)&eW1[(size_t)d * H_ + j0];

    float base_r[4];
    *(float4*)base_r = *(const float4*)&base[(size_t)b * H_ + j0];

    float w2c0[4];
#pragma unroll
    for (int i = 0; i < 4; ++i)
        w2c0[i] = eW2[(size_t)(j0 + i) * C_];

    const float eb20 = eb2[0];
    __syncthreads();

    float prev = 0.f;
    float* cb = cur0_buf + (size_t)b * TOUT;
#pragma unroll 1
    for (int t = 0; t < TOUT - 1; ++t) {   // 83 steps
        const float cur0 = (t == 0) ? xl[0] : prev;
        if (tid == 0) cb[t] = cur0;
        float pd = 0.f;
#pragma unroll
        for (int i = 0; i < 4; ++i) {
            float h = fmaf(cur0, w1r[0][i], base_r[i]);
#pragma unroll
            for (int d = 1; d < DIN; ++d)
                h = fmaf(xl[t * DIN + d], w1r[d][i], h);
            h = fmaxf(h, 0.f);
            pd = fmaf(h, w2c0[i], pd);
        }
#pragma unroll
        for (int m = 32; m > 0; m >>= 1)
            pd += __shfl_xor(pd, m, 64);
        if (lane == 0) plw[t & 1][wid] = pd;
        __syncthreads();
        prev = eb20 + plw[t & 1][0] + plw[t & 1][1] + plw[t & 1][2] + plw[t & 1][3];
    }
    if (tid == 0) cb[TOUT - 1] = prev;
}

// ===========================================================================
// Phase 2: parallel expansion. Block = 64 (b,t) rows; all 27 channels via MFMA.
// GEMM1 [64,32]@e1t20^T (+base, relu) -> h hi/lo bf16 in LDS ->
// GEMM2 vs w2t hi/lo (3 passes, fp32-exact in h and w2).
// ===========================================================================
__global__ __launch_bounds__(256, 2) void expand(
    const float* __restrict__ x, const float* __restrict__ base,
    const float* __restrict__ cur0_buf, const u16* __restrict__ e1t20,
    const u16* __restrict__ w2th, const u16* __restrict__ w2tl,
    const float* __restrict__ eb2, float* __restrict__ out)
{
    __shared__ u16 A_lds[64 * 32];
    __shared__ u16 e_lds[128 * 32];
    __shared__ u16 hh_lds[64 * 128];
    __shared__ u16 hl_lds[64 * 128];
    __shared__ u16 w2h_s[32 * 128];
    __shared__ u16 w2l_s[32 * 128];
    __shared__ float base_s[2 * 128];

    const int tid = threadIdx.x;
    const int g0 = blockIdx.x * 64;
    const int wave = tid >> 6, l = tid & 63, ml = l & 15, koct = l >> 4;
    const int b0 = g0 / 84;
    const int b1 = (b0 + 1 < B_) ? b0 + 1 : b0;

    // build A tile [64][32] bf16
    {
        const int row = tid >> 2, q = tid & 3;
        const int g = g0 + row, bb = g / 84, tt = g - bb * 84;
        u16 hw[8];
#pragma unroll
        for (int c = 0; c < 8; ++c) {
            const int k = q * 8 + c;
            float v = 0.f;
            if (k == 0) v = cur0_buf[g];
            else if (k < DIN) v = x[(size_t)bb * (T_ * DIN) + tt * DIN + k];
            hw[c] = f2bf(v);
        }
        uint4 pk;
        pk.x = hw[0] | ((unsigned)hw[1] << 16);
        pk.y = hw[2] | ((unsigned)hw[3] << 16);
        pk.z = hw[4] | ((unsigned)hw[5] << 16);
        pk.w = hw[6] | ((unsigned)hw[7] << 16);
        *(uint4*)&A_lds[row * 32 + q * 8] = pk;
    }

    int selq[4];
#pragma unroll
    for (int q = 0; q < 4; ++q)
        selq[q] = (g0 + wave * 16 + koct * 4 + q) / 84 - b0;

    __syncthreads();
    const bf16x8 afrag = *(const bf16x8*)&A_lds[(wave * 16 + ml) * 32 + koct * 8];

    f32x4 acc2[2], acc3[2];
    const f32x4 zz = {0.f, 0.f, 0.f, 0.f};
    acc2[0] = zz; acc2[1] = zz; acc3[0] = zz; acc3[1] = zz;

    for (int kc = 0; kc < 8; ++kc) {
        const int n0 = kc * 128;
        __syncthreads();   // previous chunk's stage reads complete
        {   // stage e1t20 slice [128][32]
            const int er = tid >> 1, eh = tid & 1;
            const u16* src = e1t20 + (size_t)(n0 + er) * 32 + eh * 16;
            uint4 v0 = *(const uint4*)src;
            uint4 v1 = *(const uint4*)(src + 8);
            *(uint4*)&e_lds[er * 32 + eh * 16] = v0;
            *(uint4*)&e_lds[er * 32 + eh * 16 + 8] = v1;
        }
        {   // stage w2 slices [32][128] hi/lo (slot-swizzled)
            const int wr = tid >> 3, seg = tid & 7;
            const int sl0 = ((seg * 2) ^ (wr & 15)) * 8;
            const int sl1 = ((seg * 2 + 1) ^ (wr & 15)) * 8;
            const u16* sh = w2th + (size_t)wr * 1024 + n0 + seg * 16;
            *(uint4*)&w2h_s[wr * 128 + sl0] = *(const uint4*)sh;
            *(uint4*)&w2h_s[wr * 128 + sl1] = *(const uint4*)(sh + 8);
            const u16* sl = w2tl + (size_t)wr * 1024 + n0 + seg * 16;
            *(uint4*)&w2l_s[wr * 128 + sl0] = *(const uint4*)sl;
            *(uint4*)&w2l_s[wr * 128 + sl1] = *(const uint4*)(sl + 8);
        }
        {   // stage base slice [2][128]
            const int sel = tid >> 7, c = tid & 127;
            base_s[sel * 128 + c] = base[(size_t)(sel ? b1 : b0) * 1024 + n0 + c];
        }
        __syncthreads();

        // GEMM1: h chunk [64][128], + base, relu, hi/lo split into LDS
#pragma unroll
        for (int p = 0; p < 8; ++p) {
            const bf16x8 bfrag =
                *(const bf16x8*)&e_lds[(p * 16 + ml) * 32 + koct * 8];
            f32x4 a1 = zz;
            a1 = __builtin_amdgcn_mfma_f32_16x16x32_bf16(afrag, bfrag, a1, 0, 0, 0);
            const int c16 = p * 16 + ml;
#pragma unroll
            for (int q = 0; q < 4; ++q) {
                const int row = wave * 16 + koct * 4 + q;
                float v = a1[q] + base_s[selq[q] * 128 + c16];
                v = fmaxf(v, 0.f);
                const u16 hh = f2bf(v);
                const int addr =
                    row * 128 + (((c16 >> 3) ^ (row & 7)) << 3) + (c16 & 7);
                hh_lds[addr] = hh;
                hl_lds[addr] = f2bf(v - bf2f(hh));
            }
        }
        __syncthreads();

        // GEMM2: out^T[32c][64r] partial over this 128-hidden chunk
        const int row2 = wave * 16 + ml;
#pragma unroll
        for (int ks = 0; ks < 4; ++ks) {
            const int hsl = ((ks * 4 + koct) ^ (row2 & 7)) << 3;
            const bf16x8 hhf = *(const bf16x8*)&hh_lds[row2 * 128 + hsl];
            const bf16x8 hlf = *(const bf16x8*)&hl_lds[row2 * 128 + hsl];
            const int wsl = ((ks * 4 + koct) ^ ml) << 3;
#pragma unroll
            for (int ct = 0; ct < 2; ++ct) {
                const int wrow = ct * 16 + ml;
                const bf16x8 wh = *(const bf16x8*)&w2h_s[wrow * 128 + wsl];
                const bf16x8 wl = *(const bf16x8*)&w2l_s[wrow * 128 + wsl];
                acc2[ct] = __builtin_amdgcn_mfma_f32_16x16x32_bf16(
                    wh, hhf, acc2[ct], 0, 0, 0);
                acc3[ct] = __builtin_amdgcn_mfma_f32_16x16x32_bf16(
                    wh, hlf, acc3[ct], 0, 0, 0);
                acc3[ct] = __builtin_amdgcn_mfma_f32_16x16x32_bf16(
                    wl, hhf, acc3[ct], 0, 0, 0);
            }
        }
    }

    // store: out[g][c], c = ct*16 + koct*4 + q, row g = g0 + wave*16 + ml
    const int gout = g0 + wave * 16 + ml;
#pragma unroll
    for (int ct = 0; ct < 2; ++ct) {
#pragma unroll
        for (int q = 0; q < 4; ++q) {
            const int c = ct * 16 + koct * 4 + q;
            if (c < C_)
                out[(size_t)gout * C_ + c] = acc2[ct][q] + acc3[ct][q] + eb2[c];
        }
    }
}

// ===========================================================================
// FALLBACK fp32 path (round-2 kernels) — used only if ws is too small.
// ===========================================================================
struct GemmSmem {
    float As[2][16][68];
    float Bs[2][16][64];
};

template <int RELU>
__device__ __forceinline__ void gemm_core(
    const float* __restrict__ A, int lda,
    const float* __restrict__ Bm, int ldb,
    const float* __restrict__ bias, const float* __restrict__ bias_parts,
    float* __restrict__ Cc, int ldc, int K, int tile, GemmSmem& sm)
{
    const int tid = threadIdx.x;
    const int bm = (tile >> 4) * 64, bn = (tile & 15) * 64;
    const int wave = tid >> 6, l = tid & 63;
    const int n0 = (wave & 1) * 32 + (l & 7) * 4;
    const int m0 = (wave >> 1) * 32 + (l >> 3) * 4;
    const int am = tid >> 2, akq = tid & 3;
    const int bk = tid >> 4, bnq = tid & 15;
    const float* Arow = A + (size_t)(bm + am) * lda + akq * 4;
    const float* Brow = Bm + (size_t)bk * ldb + bn + bnq * 4;
    float acc[4][4] = {};
    const int nIter = (K + 15) >> 4;
    {
        const int ak = akq * 4;
        float4 av = (ak + 4 <= K) ? *(const float4*)(Arow)
                                  : make_float4(0.f, 0.f, 0.f, 0.f);
        float4 bv = (bk < K) ? *(const float4*)(Brow)
                             : make_float4(0.f, 0.f, 0.f, 0.f);
        sm.As[0][akq * 4 + 0][am] = av.x; sm.As[0][akq * 4 + 1][am] = av.y;
        sm.As[0][akq * 4 + 2][am] = av.z; sm.As[0][akq * 4 + 3][am] = av.w;
        *(float4*)&sm.Bs[0][bk][bnq * 4] = bv;
    }
    __syncthreads();
    for (int it = 0; it < nIter; ++it) {
        const int cur = it & 1;
        const bool pf = (it + 1 < nIter);
        float4 pav, pbv;
        if (pf) {
            const int k0 = (it + 1) << 4, ak = k0 + akq * 4;
            pav = (ak + 4 <= K) ? *(const float4*)(Arow + k0)
                                : make_float4(0.f, 0.f, 0.f, 0.f);
            pbv = (k0 + bk < K) ? *(const float4*)(Brow + (size_t)k0 * ldb)
                                : make_float4(0.f, 0.f, 0.f, 0.f);
        }
#pragma unroll
        for (int kk = 0; kk < 16; ++kk) {
            float ar[4], br[4];
            *(float4*)ar = *(const float4*)&sm.As[cur][kk][m0];
            *(float4*)br = *(const float4*)&sm.Bs[cur][kk][n0];
#pragma unroll
            for (int r = 0; r < 4; ++r)
#pragma unroll
                for (int c = 0; c < 4; ++c)
                    acc[r][c] = fmaf(ar[r], br[c], acc[r][c]);
        }
        if (pf) {
            const int nb = cur ^ 1;
            sm.As[nb][akq * 4 + 0][am] = pav.x; sm.As[nb][akq * 4 + 1][am] = pav.y;
            sm.As[nb][akq * 4 + 2][am] = pav.z; sm.As[nb][akq * 4 + 3][am] = pav.w;
            *(float4*)&sm.Bs[nb][bk][bnq * 4] = pbv;
        }
        __syncthreads();
    }
    float bias4[4];
#pragma unroll
    for (int c = 0; c < 4; ++c) {
        const int col = bn + n0 + c;
        float b = bias ? bias[col] : 0.f;
        if (bias_parts)
#pragma unroll
            for (int p = 0; p < 8; ++p) b += bias_parts[p * H_ + col];
        bias4[c] = b;
    }
#pragma unroll
    for (int r = 0; r < 4; ++r) {
        float4 v; float* vp = (float*)&v;
#pragma unroll
        for (int c = 0; c < 4; ++c) {
            float t2 = acc[r][c] + bias4[c];
            if (RELU) t2 = fmaxf(t2, 0.f);
            vp[c] = t2;
        }
        *(float4*)&Cc[(size_t)(bm + m0 + r) * ldc + bn + n0] = v;
    }
}

__global__ __launch_bounds__(256) void kernelA_fb(
    const float* __restrict__ o, const float* __restrict__ oW1,
    const float* __restrict__ ob1, const float* __restrict__ oW2,
    const float* __restrict__ eW1, const float* __restrict__ ob2,
    float* __restrict__ h1, float* __restrict__ Wc, float* __restrict__ biasc)
{
    __shared__ GemmSmem sm;
    const int bid = blockIdx.x;
    if (bid < 256) {
        gemm_core<1>(o, OBJ_, oW1, H_, ob1, nullptr, h1, H_, OBJ_, bid, sm);
    } else if (bid < 512) {
        gemm_core<0>(oW2, H_, eW1 + (size_t)DIN * H_, H_, nullptr, nullptr,
                     Wc, H_, H_, bid - 256, sm);
    } else {
        const int r = bid - 512, kc = r >> 2, nb = r & 3;
        const int n = nb * 256 + (int)threadIdx.x;
        const int k0 = kc * 128;
        float acc = 0.f;
#pragma unroll 8
        for (int k = 0; k < 128; ++k)
            acc = fmaf(ob2[k0 + k], eW1[(size_t)(DIN + k0 + k) * H_ + n], acc);
        biasc[kc * H_ + n] = acc;
    }
}

__global__ __launch_bounds__(256) void kernelB_fb(
    const float* __restrict__ h1, const float* __restrict__ Wc,
    const float* __restrict__ eb1, const float* __restrict__ biasc,
    float* __restrict__ base0)
{
    __shared__ GemmSmem sm;
    gemm_core<0>(h1, H_, Wc, H_, eb1, biasc, base0, H_, H_, blockIdx.x, sm);
}

__global__ __launch_bounds__(256, 2) void expert_seq_fb(
    const float* __restrict__ x, const float* __restrict__ eW1,
    const float* __restrict__ eW2, const float* __restrict__ eb2,
    const float* __restrict__ base0, float* __restrict__ out)
{
    const int b   = blockIdx.x;
    const int tid = threadIdx.x;
    const int j0  = tid * 4;

    __shared__ float xl[T_ * DIN];
    __shared__ float pl[256 * 29];
    __shared__ float pl2[256];
    __shared__ float prevs;

    for (int idx = tid; idx < T_ * DIN; idx += 256)
        xl[idx] = x[(size_t)b * (T_ * DIN) + idx];

    float w1r[DIN][4];
#pragma unroll
    for (int d = 0; d < DIN; ++d)
        *(float4*)w1r[d] = *(const float4*)&eW1[(size_t)d * H_ + j0];

    float base_r[4];
    *(float4*)base_r = *(const float4*)&base0[(size_t)b * H_ + j0];

    float w2r[4][C_];
#pragma unroll
    for (int i = 0; i < 4; ++i)
#pragma unroll
        for (int c = 0; c < C_; ++c)
            w2r[i][c] = eW2[(size_t)(j0 + i) * C_ + c];

    const float myb = (tid < C_) ? eb2[tid] : 0.f;
    __syncthreads();

    float prev = 0.f;
#pragma unroll 1
    for (int t = 0; t < TOUT; ++t) {
        const float cur0 = (t == 0) ? xl[0] : prev;
        float h[4];
#pragma unroll
        for (int i = 0; i < 4; ++i)
            h[i] = fmaf(cur0, w1r[0][i], base_r[i]);
#pragma unroll
        for (int d = 1; d < DIN; ++d) {
            const float xv = xl[t * DIN + d];
#pragma unroll
            for (int i = 0; i < 4; ++i)
                h[i] = fmaf(xv, w1r[d][i], h[i]);
        }
#pragma unroll
        for (int i = 0; i < 4; ++i)
            h[i] = fmaxf(h[i], 0.f);
        float p[C_];
#pragma unroll
        for (int c = 0; c < C_; ++c)
            p[c] = h[0] * w2r[0][c];
#pragma unroll
        for (int i = 1; i < 4; ++i)
#pragma unroll
            for (int c = 0; c < C_; ++c)
                p[c] = fmaf(h[i], w2r[i][c], p[c]);
#pragma unroll
        for (int c = 0; c < C_; ++c)
            pl[tid * 29 + c] = p[c];
        __syncthreads();
        {
            const int c2 = tid & 31, grp = tid >> 5;
            float s = 0.f;
            if (c2 < C_) {
                const int basei = grp * 32 * 29 + c2;
#pragma unroll
                for (int s2 = 0; s2 < 32; ++s2)
                    s += pl[basei + s2 * 29];
            }
            pl2[tid] = s;
        }
        __syncthreads();
        if (tid < C_) {
            float o = myb;
#pragma unroll
            for (int g = 0; g < 8; ++g)
                o += pl2[g * 32 + tid];
            out[((size_t)b * TOUT + t) * C_ + tid] = o;
            if (tid == 0) prevs = o;
        }
        __syncthreads();
        prev = prevs;
    }
}

// ===========================================================================
extern "C" void kernel_launch(void* const* d_in, const int* in_sizes, int n_in,
                              void* d_out, int out_size, void* d_ws, size_t ws_size,
                              hipStream_t stream)
{
    const float* o   = (const float*)d_in[0];
    const float* x   = (const float*)d_in[1];
    const float* oW1 = (const float*)d_in[2];
    const float* ob1 = (const float*)d_in[3];
    const float* oW2 = (const float*)d_in[4];
    const float* ob2 = (const float*)d_in[5];
    const float* eW1 = (const float*)d_in[6];
    const float* eb1 = (const float*)d_in[7];
    const float* eW2 = (const float*)d_in[8];
    const float* eb2 = (const float*)d_in[9];

    float* outp = (float*)d_out;
    float* ws   = (float*)d_ws;
    dim3 blk(256);

    const size_t NEED2 = 38293504;
    if (ws_size >= NEED2) {
        float* p_h1   = ws;                       // 3*1048576
        float* p_wc   = ws + 3145728;             // 1048576
        float* biasWc = ws + 4194304;             // 1024
        float* cur0b  = ws + 4195328;             // 86016
        u16*   ub     = (u16*)(ws + 4281344);
        u16 *o_bf  = ub,             *bW1t = ub + 3145728;
        u16 *bE1t  = ub + 6291456,   *o2bf = ub + 7340032;
        u16 *h1bf  = ub + 8388608,   *Wct  = ub + 9437184;
        u16 *w2th  = ub + 10485760,  *w2tl = ub + 10518528;
        u16 *e1t20 = ub + 10551296;
        float* base = p_h1;   // reuse p_h1[0] after epilogue2 consumed it

        convertK2<<<dim3(1704), blk, 0, stream>>>(o, oW1, eW1, oW2, eW2, ob2,
                                                  eb1, o_bf, bW1t, bE1t, o2bf,
                                                  w2th, w2tl, e1t20, biasWc);
        kernelA2<<<dim3(512), blk, 0, stream>>>(o_bf, bW1t, o2bf, bE1t,
                                                p_h1, p_wc);
        epilogue2<<<dim3(512), blk, 0, stream>>>(p_h1, p_wc, ob1, h1bf, Wct);
        kernelB2<<<dim3(128), blk, 0, stream>>>(h1bf, Wct, biasWc, base);
        chain_seq<<<dim3(B_), blk, 0, stream>>>(x, eW1, eW2, eb2, base, cur0b);
        expand<<<dim3(1344), blk, 0, stream>>>(x, base, cur0b, e1t20,
                                               w2th, w2tl, eb2, outp);
    } else {
        const size_t MF = (size_t)H_ * H_;
        float* h1    = ws;
        float* Wc    = ws + MF;
        float* base0 = ws + 2 * MF;
        float* biasc = outp;
        kernelA_fb<<<dim3(544), blk, 0, stream>>>(o, oW1, ob1, oW2, eW1, ob2,
                                                  h1, Wc, biasc);
        kernelB_fb<<<dim3(256), blk, 0, stream>>>(h1, Wc, eb1, biasc, base0);
        expert_seq_fb<<<dim3(B_), blk, 0, stream>>>(x, eW1, eW2, eb2,
                                                    base0, outp);
    }
}

// Round 5
// 199.416 us; speedup vs baseline: 2.8600x; 1.2093x over previous
//
#include <hip/hip_runtime.h>
#include <hip/hip_bf16.h>

#define B_   1024
#define T_   85
#define DIN  20
#define H_   1024
#define C_   27
#define OBJ_ (T_ * 36)   // 3060
#define TOUT (T_ - 1)    // 84

typedef unsigned short u16;
typedef __attribute__((ext_vector_type(8))) short bf16x8;
typedef __attribute__((ext_vector_type(4))) float f32x4;

__device__ __forceinline__ u16 f2bf(float f) {
    __hip_bfloat16 h = __float2bfloat16(f);
    return *reinterpret_cast<u16*>(&h);
}
__device__ __forceinline__ float bf2f(u16 u) {
    __hip_bfloat16 h;
    *reinterpret_cast<u16*>(&h) = u;
    return __bfloat162float(h);
}

// ===========================================================================
// convertK2: all input conversions in one launch.
//  [0,512)     o [1024][3060] f32 -> o_bf [1024][3072] bf16 (pad 0)
//  [512,1280)  oW1 [3060][1024] -> bW1t [1024 n][3072 k] bf16 (transpose)
//  [1280,1536) eW1[20:] [1024][1024] -> bE1t [1024][1024] bf16 (transpose)
//  [1536,1664) oW2 -> o2bf bf16
//  [1664,1696) eW2 [1024][27] -> w2th [32][1024] (transpose, bf16)
//  [1696,1700) eW1[0:20] -> e1t20 [1024 n][32 k] bf16 (transpose, pad 0)
//  [1700,1704) biasWc[n] = eb1[n] + sum_k ob2[k]*eW1[20+k][n]
// ===========================================================================
__global__ __launch_bounds__(256) void convertK2(
    const float* __restrict__ o, const float* __restrict__ oW1,
    const float* __restrict__ eW1, const float* __restrict__ oW2,
    const float* __restrict__ eW2, const float* __restrict__ ob2,
    const float* __restrict__ eb1,
    u16* __restrict__ o_bf, u16* __restrict__ bW1t, u16* __restrict__ bE1t,
    u16* __restrict__ o2bf, u16* __restrict__ w2th,
    u16* __restrict__ e1t20, float* __restrict__ biasWc)
{
    __shared__ float tl[64][65];
    const int bid = blockIdx.x, t = threadIdx.x;

    if (bid < 512) {
        for (int it = 0; it < 6; ++it) {
            const int idx = (bid * 256 + t) + it * 131072;
            const int row = idx / 768, g = idx - row * 768;
            float4 v = make_float4(0.f, 0.f, 0.f, 0.f);
            if (g < 765) v = *(const float4*)(o + (size_t)row * 3060 + g * 4);
            const float* vp = (const float*)&v;
            ushort4 uh;
            uh.x = f2bf(vp[0]); uh.y = f2bf(vp[1]);
            uh.z = f2bf(vp[2]); uh.w = f2bf(vp[3]);
            *(ushort4*)(o_bf + (size_t)row * 3072 + g * 4) = uh;
        }
    } else if (bid < 1536) {
        const bool isW1 = (bid < 1280);
        const int idx = isW1 ? (bid - 512) : (bid - 1280);
        const int k0 = (idx >> 4) * 64, n0 = (idx & 15) * 64;
        const float* src = isW1 ? oW1 : (eW1 + (size_t)DIN * H_);
        const int Ksrc = isW1 ? 3060 : 1024;
        u16* dst = isW1 ? bW1t : bE1t;
        const int ldk = isW1 ? 3072 : 1024;
#pragma unroll
        for (int r = 0; r < 4; ++r) {
            const int k = k0 + r * 16 + (t >> 4);
            float4 v = make_float4(0.f, 0.f, 0.f, 0.f);
            if (k < Ksrc)
                v = *(const float4*)(src + (size_t)k * 1024 + n0 + (t & 15) * 4);
            const float* vp = (const float*)&v;
#pragma unroll
            for (int j = 0; j < 4; ++j)
                tl[r * 16 + (t >> 4)][(t & 15) * 4 + j] = vp[j];
        }
        __syncthreads();
#pragma unroll
        for (int r = 0; r < 4; ++r) {
            const int n = r * 16 + (t >> 4);
            ushort4 u;
            u.x = f2bf(tl[(t & 15) * 4 + 0][n]);
            u.y = f2bf(tl[(t & 15) * 4 + 1][n]);
            u.z = f2bf(tl[(t & 15) * 4 + 2][n]);
            u.w = f2bf(tl[(t & 15) * 4 + 3][n]);
            *(ushort4*)(dst + (size_t)(n0 + n) * ldk + k0 + (t & 15) * 4) = u;
        }
    } else if (bid < 1664) {
        const int base = (bid - 1536) * 256 + t;
#pragma unroll
        for (int it = 0; it < 8; ++it) {
            const int g = base + it * 32768;
            float4 v = *(const float4*)(oW2 + (size_t)g * 4);
            const float* vp = (const float*)&v;
            ushort4 uh;
            uh.x = f2bf(vp[0]); uh.y = f2bf(vp[1]);
            uh.z = f2bf(vp[2]); uh.w = f2bf(vp[3]);
            *(ushort4*)(o2bf + (size_t)g * 4) = uh;
        }
    } else if (bid < 1696) {
        const int c = bid - 1664;
#pragma unroll
        for (int kk = 0; kk < 4; ++kk) {
            const int k = kk * 256 + t;
            const float v = (c < C_) ? eW2[(size_t)k * C_ + c] : 0.f;
            w2th[(size_t)c * 1024 + k] = f2bf(v);
        }
    } else if (bid < 1700) {
        const int n = (bid - 1696) * 256 + t;
        u16 buf[32];
#pragma unroll
        for (int k = 0; k < 32; ++k)
            buf[k] = (k < DIN) ? f2bf(eW1[(size_t)k * H_ + n]) : (u16)0;
#pragma unroll
        for (int q = 0; q < 4; ++q)
            *(uint4*)(e1t20 + (size_t)n * 32 + q * 8) = *(uint4*)&buf[q * 8];
    } else {
        const int n = (bid - 1700) * 256 + t;
        float s = eb1[n];
        for (int k = 0; k < 1024; ++k)
            s = fmaf(ob2[k], eW1[(size_t)(DIN + k) * H_ + n], s);
        biasWc[n] = s;
    }
}

// ---------------------------------------------------------------------------
// MFMA GEMM tile (single bf16 A): C[gm0+128, gn0+64] = A @ Bt^T (+bias).
// ---------------------------------------------------------------------------
template <int BN>
__device__ __forceinline__ void gemm_mfma_tile(
    const u16* __restrict__ A0, const u16* __restrict__ Bt,
    float* __restrict__ C, const float* __restrict__ bias,
    int ldK, int nk1, int gm0, int gn0, char* lds)
{
    constexpr int FN    = BN / 32;
    constexpr int WNw   = BN / 2;
    constexpr int BR    = BN / 64;
    constexpr int BUFSZ = 8192 + BN * 64;

    const int tid  = threadIdx.x;
    const int wave = tid >> 6, l = tid & 63, ml = l & 15, koct = l >> 4;
    const int wm = wave >> 1, wn = wave & 1;
    const int swz = koct ^ ((ml >> 1) & 3);
    const int a_ro = (wm * 64 + ml) * 64 + swz * 16;
    const int b_ro = (wn * WNw + ml) * 64 + swz * 16;

    const int sm = tid >> 2, sq = tid & 3;
    int wAo[2], wBo[BR];
    size_t gAo[2], gBo[BR];
#pragma unroll
    for (int q = 0; q < 2; ++q) {
        const int m = q * 64 + sm;
        wAo[q] = m * 64 + ((sq ^ ((m >> 1) & 3)) * 16);
        gAo[q] = (size_t)(gm0 + m) * ldK * 2 + sq * 16;
    }
#pragma unroll
    for (int q = 0; q < BR; ++q) {
        const int n = q * 64 + sm;
        wBo[q] = n * 64 + ((sq ^ ((n >> 1) & 3)) * 16);
        gBo[q] = (size_t)(gn0 + n) * ldK * 2 + sq * 16;
    }

    f32x4 acc[4][FN];
    const f32x4 zz = {0.f, 0.f, 0.f, 0.f};
#pragma unroll
    for (int i = 0; i < 4; ++i)
#pragma unroll
        for (int j = 0; j < FN; ++j) acc[i][j] = zz;

    const char* A0c = (const char*)A0;
    const char* Btc = (const char*)Bt;

    uint4 st[2 + BR];
    auto stage = [&](int kt) {
        const size_t koff = (size_t)kt * 64;
        st[0] = *(const uint4*)(A0c + gAo[0] + koff);
        st[1] = *(const uint4*)(A0c + gAo[1] + koff);
#pragma unroll
        for (int q = 0; q < BR; ++q)
            st[2 + q] = *(const uint4*)(Btc + gBo[q] + koff);
    };
    auto dswrite = [&](int buf) {
        char* d = lds + buf * BUFSZ;
        *(uint4*)(d + wAo[0]) = st[0];
        *(uint4*)(d + wAo[1]) = st[1];
#pragma unroll
        for (int q = 0; q < BR; ++q)
            *(uint4*)(d + 8192 + wBo[q]) = st[2 + q];
    };
    auto compute = [&](int buf) {
        const char* As = lds + buf * BUFSZ;
        const char* Bs = As + 8192;
        bf16x8 af[4], bfv[FN];
#pragma unroll
        for (int fm = 0; fm < 4; ++fm)
            af[fm] = *(const bf16x8*)(As + a_ro + fm * 1024);
#pragma unroll
        for (int fn = 0; fn < FN; ++fn)
            bfv[fn] = *(const bf16x8*)(Bs + b_ro + fn * 1024);
#pragma unroll
        for (int fm = 0; fm < 4; ++fm)
#pragma unroll
            for (int fn = 0; fn < FN; ++fn)
                acc[fm][fn] = __builtin_amdgcn_mfma_f32_16x16x32_bf16(
                    af[fm], bfv[fn], acc[fm][fn], 0, 0, 0);
    };

    stage(0); dswrite(0); __syncthreads();
    for (int kt = 0; kt < nk1; ++kt) {
        if (kt + 1 < nk1) stage(kt + 1);
        compute(kt & 1);
        if (kt + 1 < nk1) dswrite((kt + 1) & 1);
        __syncthreads();
    }

    float br[FN];
#pragma unroll
    for (int fn = 0; fn < FN; ++fn)
        br[fn] = bias ? bias[gn0 + wn * WNw + fn * 16 + ml] : 0.f;
#pragma unroll
    for (int fm = 0; fm < 4; ++fm) {
        const int rowb = gm0 + wm * 64 + fm * 16 + koct * 4;
#pragma unroll
        for (int fn = 0; fn < FN; ++fn) {
            const int col = gn0 + wn * WNw + fn * 16 + ml;
#pragma unroll
            for (int r = 0; r < 4; ++r)
                C[(size_t)(rowb + r) * 1024 + col] = acc[fm][fn][r] + br[fn];
        }
    }
}

// kernelA2: [0,384) GEMM1 split-K3 -> p_h1[c]; [384,512) Wc -> p_wc
__global__ __launch_bounds__(256) void kernelA2(
    const u16* __restrict__ o_bf, const u16* __restrict__ bW1t,
    const u16* __restrict__ o2bf, const u16* __restrict__ bE1t,
    float* __restrict__ p_h1, float* __restrict__ p_wc)
{
    __shared__ alignas(16) char lds[2 * 12288];
    const int bid = blockIdx.x;
    if (bid < 384) {
        const int c = bid >> 7, tl = bid & 127;
        gemm_mfma_tile<64>(o_bf + c * 1024, bW1t + c * 1024,
                           p_h1 + (size_t)c * 1048576, nullptr, 3072, 32,
                           (tl >> 4) * 128, (tl & 15) * 64, lds);
    } else {
        const int tl = bid - 384;
        gemm_mfma_tile<64>(o2bf, bE1t, p_wc, nullptr, 1024, 32,
                           (tl >> 4) * 128, (tl & 15) * 64, lds);
    }
}

// epilogue2: [0,256) h1bf = bf16(relu(p0+p1+p2+ob1)); [256,512) Wct = bf16(p_wc^T)
__global__ __launch_bounds__(256) void epilogue2(
    const float* __restrict__ p_h1, const float* __restrict__ p_wc,
    const float* __restrict__ ob1,
    u16* __restrict__ h1bf, u16* __restrict__ Wct)
{
    __shared__ float tl[64][65];
    const int bid = blockIdx.x, t = threadIdx.x;
    if (bid < 256) {
#pragma unroll
        for (int it = 0; it < 4; ++it) {
            const int g = bid * 1024 + it * 256 + t;
            const size_t e = (size_t)g * 4;
            float4 a = *(const float4*)(p_h1 + e);
            float4 b = *(const float4*)(p_h1 + 1048576 + e);
            float4 c = *(const float4*)(p_h1 + 2097152 + e);
            float4 s = *(const float4*)(ob1 + (e & 1023));
            const float *ap = (const float*)&a, *bp = (const float*)&b,
                        *cp = (const float*)&c, *sp = (const float*)&s;
            ushort4 uh;
            u16* up = (u16*)&uh;
#pragma unroll
            for (int j = 0; j < 4; ++j)
                up[j] = f2bf(fmaxf(ap[j] + bp[j] + cp[j] + sp[j], 0.f));
            *(ushort4*)(h1bf + e) = uh;
        }
    } else {
        const int idx = bid - 256;
        const int k0 = (idx >> 4) * 64, n0 = (idx & 15) * 64;
#pragma unroll
        for (int r = 0; r < 4; ++r) {
            const int k = k0 + r * 16 + (t >> 4);
            float4 v = *(const float4*)(p_wc + (size_t)k * 1024 + n0 + (t & 15) * 4);
            const float* vp = (const float*)&v;
#pragma unroll
            for (int j = 0; j < 4; ++j)
                tl[r * 16 + (t >> 4)][(t & 15) * 4 + j] = vp[j];
        }
        __syncthreads();
#pragma unroll
        for (int r = 0; r < 4; ++r) {
            const int n = r * 16 + (t >> 4);
            ushort4 u;
            u.x = f2bf(tl[(t & 15) * 4 + 0][n]);
            u.y = f2bf(tl[(t & 15) * 4 + 1][n]);
            u.z = f2bf(tl[(t & 15) * 4 + 2][n]);
            u.w = f2bf(tl[(t & 15) * 4 + 3][n]);
            *(ushort4*)(Wct + (size_t)(n0 + n) * 1024 + k0 + (t & 15) * 4) = u;
        }
    }
}

// kernelB2 split-K2: base0 = h1bf[:, :512] @ Wct[:, :512]^T
//                    base1 = h1bf[:, 512:] @ Wct[:, 512:]^T + biasWc
__global__ __launch_bounds__(256) void kernelB2(
    const u16* __restrict__ h1bf, const u16* __restrict__ Wct,
    const float* __restrict__ biasWc,
    float* __restrict__ base0, float* __restrict__ base1)
{
    __shared__ alignas(16) char lds[2 * 12288];
    const int bid = blockIdx.x;
    const int p = bid >> 7, tl = bid & 127;
    gemm_mfma_tile<64>(h1bf + p * 512, Wct + p * 512,
                       p ? base1 : base0, p ? biasWc : nullptr,
                       1024, 16, (tl >> 4) * 128, (tl & 15) * 64, lds);
}

// ===========================================================================
// Phase 1: sequential chain, channel 0 only. One block per batch row.
// ===========================================================================
__global__ __launch_bounds__(256, 4) void chain_seq(
    const float* __restrict__ x, const float* __restrict__ eW1,
    const float* __restrict__ eW2, const float* __restrict__ eb2,
    const float* __restrict__ base0, const float* __restrict__ base1,
    float* __restrict__ cur0_buf)
{
    const int b = blockIdx.x, tid = threadIdx.x;
    const int j0 = tid * 4;
    const int wid = tid >> 6, lane = tid & 63;

    __shared__ float xl[T_ * DIN];
    __shared__ float plw[2][4];

    for (int i = tid; i < T_ * DIN; i += 256)
        xl[i] = x[(size_t)b * (T_ * DIN) + i];

    float w1r[DIN][4];
#pragma unroll
    for (int d = 0; d < DIN; ++d)
        *(float4*)w1r[d] = *(const float4*)&eW1[(size_t)d * H_ + j0];

    float base_r[4];
    {
        float4 b0v = *(const float4*)&base0[(size_t)b * H_ + j0];
        float4 b1v = *(const float4*)&base1[(size_t)b * H_ + j0];
        base_r[0] = b0v.x + b1v.x; base_r[1] = b0v.y + b1v.y;
        base_r[2] = b0v.z + b1v.z; base_r[3] = b0v.w + b1v.w;
    }

    float w2c0[4];
#pragma unroll
    for (int i = 0; i < 4; ++i)
        w2c0[i] = eW2[(size_t)(j0 + i) * C_];

    const float eb20 = eb2[0];
    __syncthreads();

    float prev = 0.f;
    float* cb = cur0_buf + (size_t)b * TOUT;
#pragma unroll 1
    for (int t = 0; t < TOUT - 1; ++t) {   // 83 steps
        const float cur0 = (t == 0) ? xl[0] : prev;
        if (tid == 0) cb[t] = cur0;
        float pd = 0.f;
#pragma unroll
        for (int i = 0; i < 4; ++i) {
            float h = fmaf(cur0, w1r[0][i], base_r[i]);
#pragma unroll
            for (int d = 1; d < DIN; ++d)
                h = fmaf(xl[t * DIN + d], w1r[d][i], h);
            h = fmaxf(h, 0.f);
            pd = fmaf(h, w2c0[i], pd);
        }
#pragma unroll
        for (int m = 32; m > 0; m >>= 1)
            pd += __shfl_xor(pd, m, 64);
        if (lane == 0) plw[t & 1][wid] = pd;
        __syncthreads();
        prev = eb20 + plw[t & 1][0] + plw[t & 1][1] + plw[t & 1][2] + plw[t & 1][3];
    }
    if (tid == 0) cb[TOUT - 1] = prev;
}

// ===========================================================================
// Phase 2: parallel expansion (rewritten).
// Block = 64 (b,t) rows. 8 chunks of 128 hidden units.
// GEMM1': mfma(e1_frag, x_frag) -> H^T frag: lane holds 4 consecutive j at
// fixed g -> one packed ds_write_b64 into row-major h[g][j] (swizzled slots).
// GEMM2: out^T = mfma(w2_frag, h_frag) accumulated over chunks.
// 16B-slot XOR swizzle (slot ^ (row&15)) makes all LDS traffic conflict-free.
// h rows are wave-private (no barrier between GEMM1 writes and GEMM2 reads).
// ===========================================================================
__global__ __launch_bounds__(256, 4) void expand(
    const float* __restrict__ x, const float* __restrict__ base0,
    const float* __restrict__ base1, const float* __restrict__ cur0_buf,
    const u16* __restrict__ e1t20, const u16* __restrict__ w2th,
    const float* __restrict__ eb2, float* __restrict__ out)
{
    __shared__ u16 A_lds[64 * 32];     // x-input tile, row-major
    __shared__ u16 e_lds[128 * 32];    // e1 slice, row-major
    __shared__ u16 h_lds[64 * 128];    // h, row-major, 16B-slot swizzled
    __shared__ u16 w2_s[32 * 128];     // w2 slice, 16B-slot swizzled
    __shared__ float base_s[2 * 128];

    const int tid = threadIdx.x;
    const int g0 = blockIdx.x * 64;
    const int w = tid >> 6, l = tid & 63, ml = l & 15, koct = l >> 4;
    const int b0 = g0 / 84;
    const int b1 = (b0 + 1 < B_) ? b0 + 1 : b0;

    // build A tile [64][32] bf16
    {
        const int row = tid >> 2, q = tid & 3;
        const int g = g0 + row, bb = g / 84, tt = g - bb * 84;
        u16 hw[8];
#pragma unroll
        for (int c = 0; c < 8; ++c) {
            const int k = q * 8 + c;
            float v = 0.f;
            if (k == 0) v = cur0_buf[g];
            else if (k < DIN) v = x[(size_t)bb * (T_ * DIN) + tt * DIN + k];
            hw[c] = f2bf(v);
        }
        uint4 pk;
        pk.x = hw[0] | ((unsigned)hw[1] << 16);
        pk.y = hw[2] | ((unsigned)hw[3] << 16);
        pk.z = hw[4] | ((unsigned)hw[5] << 16);
        pk.w = hw[6] | ((unsigned)hw[7] << 16);
        *(uint4*)&A_lds[row * 32 + q * 8] = pk;
    }

    const int grow = w * 16 + ml;          // this thread's g-row (0..63)
    const int g = g0 + grow;
    const int sel = g / 84 - b0;           // 0 or 1
    __syncthreads();
    const bf16x8 xfrag = *(const bf16x8*)&A_lds[grow * 32 + koct * 8];

    f32x4 acc[2];
    const f32x4 zz = {0.f, 0.f, 0.f, 0.f};
    acc[0] = zz; acc[1] = zz;

#pragma unroll 1
    for (int kc = 0; kc < 8; ++kc) {
        const int n0 = kc * 128;
        if (kc) __syncthreads();           // previous chunk's reads complete
        {   // stage e1 slice (contiguous 8KB)
            const u16* src = e1t20 + n0 * 32 + tid * 16;
            *(uint4*)&e_lds[tid * 16]     = *(const uint4*)src;
            *(uint4*)&e_lds[tid * 16 + 8] = *(const uint4*)(src + 8);
        }
        {   // stage w2 slice [32][128], slot-swizzled
            const int wr = tid >> 3, sg = tid & 7;
            const u16* srcw = w2th + (size_t)wr * 1024 + n0 + sg * 16;
            const int s0 = (sg * 2) ^ (wr & 15), s1 = (sg * 2 + 1) ^ (wr & 15);
            *(uint4*)&w2_s[wr * 128 + s0 * 8] = *(const uint4*)srcw;
            *(uint4*)&w2_s[wr * 128 + s1 * 8] = *(const uint4*)(srcw + 8);
        }
        {   // stage base slice [2][128] (base0+base1)
            const int bs = tid >> 7, c = tid & 127;
            const size_t rb = (size_t)(bs ? b1 : b0) * H_ + n0 + c;
            base_s[bs * 128 + c] = base0[rb] + base1[rb];
        }
        __syncthreads();

        // GEMM1': per p, C[j_local][g_local]; this lane: j = p*16+koct*4+q, g fixed
#pragma unroll
        for (int p = 0; p < 8; ++p) {
            const bf16x8 ef = *(const bf16x8*)&e_lds[(p * 16 + ml) * 32 + koct * 8];
            f32x4 c1 = zz;
            c1 = __builtin_amdgcn_mfma_f32_16x16x32_bf16(ef, xfrag, c1, 0, 0, 0);
            u16 hq[4];
#pragma unroll
            for (int q = 0; q < 4; ++q) {
                const int j = p * 16 + koct * 4 + q;
                const float v = c1[q] + base_s[sel * 128 + j];
                hq[q] = f2bf(fmaxf(v, 0.f));
            }
            uint2 pk;
            pk.x = hq[0] | ((unsigned)hq[1] << 16);
            pk.y = hq[2] | ((unsigned)hq[3] << 16);
            const int s16 = (p * 2 + (koct >> 1)) ^ ml;
            *(uint2*)&h_lds[grow * 128 + s16 * 8 + (koct & 1) * 4] = pk;
        }
        // h rows are wave-private: in-wave LDS ordering suffices, no barrier.

        // GEMM2: acc[ct] += w2_slice^T-chunk @ h-chunk
#pragma unroll
        for (int ks = 0; ks < 4; ++ks) {
            const int sl = (((ks * 4 + koct) ^ ml)) * 8;
            const bf16x8 hf = *(const bf16x8*)&h_lds[grow * 128 + sl];
#pragma unroll
            for (int ct = 0; ct < 2; ++ct) {
                const bf16x8 wf = *(const bf16x8*)&w2_s[(ct * 16 + ml) * 128 + sl];
                acc[ct] = __builtin_amdgcn_mfma_f32_16x16x32_bf16(
                    wf, hf, acc[ct], 0, 0, 0);
            }
        }
    }

    // epilogue: C rows = channels (koct*4+q within ct*16), cols = g
#pragma unroll
    for (int ct = 0; ct < 2; ++ct) {
#pragma unroll
        for (int q = 0; q < 4; ++q) {
            const int c = ct * 16 + koct * 4 + q;
            if (c < C_)
                out[(size_t)g * C_ + c] = acc[ct][q] + eb2[c];
        }
    }
}

// ===========================================================================
// FALLBACK fp32 path (round-2 kernels) — used only if ws is too small.
// ===========================================================================
struct GemmSmem {
    float As[2][16][68];
    float Bs[2][16][64];
};

template <int RELU>
__device__ __forceinline__ void gemm_core(
    const float* __restrict__ A, int lda,
    const float* __restrict__ Bm, int ldb,
    const float* __restrict__ bias, const float* __restrict__ bias_parts,
    float* __restrict__ Cc, int ldc, int K, int tile, GemmSmem& sm)
{
    const int tid = threadIdx.x;
    const int bm = (tile >> 4) * 64, bn = (tile & 15) * 64;
    const int wave = tid >> 6, l = tid & 63;
    const int n0 = (wave & 1) * 32 + (l & 7) * 4;
    const int m0 = (wave >> 1) * 32 + (l >> 3) * 4;
    const int am = tid >> 2, akq = tid & 3;
    const int bk = tid >> 4, bnq = tid & 15;
    const float* Arow = A + (size_t)(bm + am) * lda + akq * 4;
    const float* Brow = Bm + (size_t)bk * ldb + bn + bnq * 4;
    float acc[4][4] = {};
    const int nIter = (K + 15) >> 4;
    {
        const int ak = akq * 4;
        float4 av = (ak + 4 <= K) ? *(const float4*)(Arow)
                                  : make_float4(0.f, 0.f, 0.f, 0.f);
        float4 bv = (bk < K) ? *(const float4*)(Brow)
                             : make_float4(0.f, 0.f, 0.f, 0.f);
        sm.As[0][akq * 4 + 0][am] = av.x; sm.As[0][akq * 4 + 1][am] = av.y;
        sm.As[0][akq * 4 + 2][am] = av.z; sm.As[0][akq * 4 + 3][am] = av.w;
        *(float4*)&sm.Bs[0][bk][bnq * 4] = bv;
    }
    __syncthreads();
    for (int it = 0; it < nIter; ++it) {
        const int cur = it & 1;
        const bool pf = (it + 1 < nIter);
        float4 pav, pbv;
        if (pf) {
            const int k0 = (it + 1) << 4, ak = k0 + akq * 4;
            pav = (ak + 4 <= K) ? *(const float4*)(Arow + k0)
                                : make_float4(0.f, 0.f, 0.f, 0.f);
            pbv = (k0 + bk < K) ? *(const float4*)(Brow + (size_t)k0 * ldb)
                                : make_float4(0.f, 0.f, 0.f, 0.f);
        }
#pragma unroll
        for (int kk = 0; kk < 16; ++kk) {
            float ar[4], br[4];
            *(float4*)ar = *(const float4*)&sm.As[cur][kk][m0];
            *(float4*)br = *(const float4*)&sm.Bs[cur][kk][n0];
#pragma unroll
            for (int r = 0; r < 4; ++r)
#pragma unroll
                for (int c = 0; c < 4; ++c)
                    acc[r][c] = fmaf(ar[r], br[c], acc[r][c]);
        }
        if (pf) {
            const int nb = cur ^ 1;
            sm.As[nb][akq * 4 + 0][am] = pav.x; sm.As[nb][akq * 4 + 1][am] = pav.y;
            sm.As[nb][akq * 4 + 2][am] = pav.z; sm.As[nb][akq * 4 + 3][am] = pav.w;
            *(float4*)&sm.Bs[nb][bk][bnq * 4] = pbv;
        }
        __syncthreads();
    }
    float bias4[4];
#pragma unroll
    for (int c = 0; c < 4; ++c) {
        const int col = bn + n0 + c;
        float b = bias ? bias[col] : 0.f;
        if (bias_parts)
#pragma unroll
            for (int p = 0; p < 8; ++p) b += bias_parts[p * H_ + col];
        bias4[c] = b;
    }
#pragma unroll
    for (int r = 0; r < 4; ++r) {
        float4 v; float* vp = (float*)&v;
#pragma unroll
        for (int c = 0; c < 4; ++c) {
            float t2 = acc[r][c] + bias4[c];
            if (RELU) t2 = fmaxf(t2, 0.f);
            vp[c] = t2;
        }
        *(float4*)&Cc[(size_t)(bm + m0 + r) * ldc + bn + n0] = v;
    }
}

__global__ __launch_bounds__(256) void kernelA_fb(
    const float* __restrict__ o, const float* __restrict__ oW1,
    const float* __restrict__ ob1, const float* __restrict__ oW2,
    const float* __restrict__ eW1, const float* __restrict__ ob2,
    float* __restrict__ h1, float* __restrict__ Wc, float* __restrict__ biasc)
{
    __shared__ GemmSmem sm;
    const int bid = blockIdx.x;
    if (bid < 256) {
        gemm_core<1>(o, OBJ_, oW1, H_, ob1, nullptr, h1, H_, OBJ_, bid, sm);
    } else if (bid < 512) {
        gemm_core<0>(oW2, H_, eW1 + (size_t)DIN * H_, H_, nullptr, nullptr,
                     Wc, H_, H_, bid - 256, sm);
    } else {
        const int r = bid - 512, kc = r >> 2, nb = r & 3;
        const int n = nb * 256 + (int)threadIdx.x;
        const int k0 = kc * 128;
        float acc = 0.f;
#pragma unroll 8
        for (int k = 0; k < 128; ++k)
            acc = fmaf(ob2[k0 + k], eW1[(size_t)(DIN + k0 + k) * H_ + n], acc);
        biasc[kc * H_ + n] = acc;
    }
}

__global__ __launch_bounds__(256) void kernelB_fb(
    const float* __restrict__ h1, const float* __restrict__ Wc,
    const float* __restrict__ eb1, const float* __restrict__ biasc,
    float* __restrict__ base0)
{
    __shared__ GemmSmem sm;
    gemm_core<0>(h1, H_, Wc, H_, eb1, biasc, base0, H_, H_, blockIdx.x, sm);
}

__global__ __launch_bounds__(256, 2) void expert_seq_fb(
    const float* __restrict__ x, const float* __restrict__ eW1,
    const float* __restrict__ eW2, const float* __restrict__ eb2,
    const float* __restrict__ base0, float* __restrict__ out)
{
    const int b   = blockIdx.x;
    const int tid = threadIdx.x;
    const int j0  = tid * 4;

    __shared__ float xl[T_ * DIN];
    __shared__ float pl[256 * 29];
    __shared__ float pl2[256];
    __shared__ float prevs;

    for (int idx = tid; idx < T_ * DIN; idx += 256)
        xl[idx] = x[(size_t)b * (T_ * DIN) + idx];

    float w1r[DIN][4];
#pragma unroll
    for (int d = 0; d < DIN; ++d)
        *(float4*)w1r[d] = *(const float4*)&eW1[(size_t)d * H_ + j0];

    float base_r[4];
    *(float4*)base_r = *(const float4*)&base0[(size_t)b * H_ + j0];

    float w2r[4][C_];
#pragma unroll
    for (int i = 0; i < 4; ++i)
#pragma unroll
        for (int c = 0; c < C_; ++c)
            w2r[i][c] = eW2[(size_t)(j0 + i) * C_ + c];

    const float myb = (tid < C_) ? eb2[tid] : 0.f;
    __syncthreads();

    float prev = 0.f;
#pragma unroll 1
    for (int t = 0; t < TOUT; ++t) {
        const float cur0 = (t == 0) ? xl[0] : prev;
        float h[4];
#pragma unroll
        for (int i = 0; i < 4; ++i)
            h[i] = fmaf(cur0, w1r[0][i], base_r[i]);
#pragma unroll
        for (int d = 1; d < DIN; ++d) {
            const float xv = xl[t * DIN + d];
#pragma unroll
            for (int i = 0; i < 4; ++i)
                h[i] = fmaf(xv, w1r[d][i], h[i]);
        }
#pragma unroll
        for (int i = 0; i < 4; ++i)
            h[i] = fmaxf(h[i], 0.f);
        float p[C_];
#pragma unroll
        for (int c = 0; c < C_; ++c)
            p[c] = h[0] * w2r[0][c];
#pragma unroll
        for (int i = 1; i < 4; ++i)
#pragma unroll
            for (int c = 0; c < C_; ++c)
                p[c] = fmaf(h[i], w2r[i][c], p[c]);
#pragma unroll
        for (int c = 0; c < C_; ++c)
            pl[tid * 29 + c] = p[c];
        __syncthreads();
        {
            const int c2 = tid & 31, grp = tid >> 5;
            float s = 0.f;
            if (c2 < C_) {
                const int basei = grp * 32 * 29 + c2;
#pragma unroll
                for (int s2 = 0; s2 < 32; ++s2)
                    s += pl[basei + s2 * 29];
            }
            pl2[tid] = s;
        }
        __syncthreads();
        if (tid < C_) {
            float o = myb;
#pragma unroll
            for (int g = 0; g < 8; ++g)
                o += pl2[g * 32 + tid];
            out[((size_t)b * TOUT + t) * C_ + tid] = o;
            if (tid == 0) prevs = o;
        }
        __syncthreads();
        prev = prevs;
    }
}

// ===========================================================================
extern "C" void kernel_launch(void* const* d_in, const int* in_sizes, int n_in,
                              void* d_out, int out_size, void* d_ws, size_t ws_size,
                              hipStream_t stream)
{
    const float* o   = (const float*)d_in[0];
    const float* x   = (const float*)d_in[1];
    const float* oW1 = (const float*)d_in[2];
    const float* ob1 = (const float*)d_in[3];
    const float* oW2 = (const float*)d_in[4];
    const float* ob2 = (const float*)d_in[5];
    const float* eW1 = (const float*)d_in[6];
    const float* eb1 = (const float*)d_in[7];
    const float* eW2 = (const float*)d_in[8];
    const float* eb2 = (const float*)d_in[9];

    float* outp = (float*)d_out;
    float* ws   = (float*)d_ws;
    dim3 blk(256);

    const size_t NEED2 = 38293504;
    if (ws_size >= NEED2) {
        float* p_h1   = ws;                       // 3*1048576 f
        float* p_wc   = ws + 3145728;             // 1048576 f
        float* biasWc = ws + 4194304;             // 1024 f
        float* cur0b  = ws + 4195328;             // 86016 f
        u16*   ub     = (u16*)(ws + 4281344);
        u16 *o_bf  = ub,             *bW1t = ub + 3145728;
        u16 *bE1t  = ub + 6291456,   *o2bf = ub + 7340032;
        u16 *h1bf  = ub + 8388608,   *Wct  = ub + 9437184;
        u16 *w2th  = ub + 10485760;
        u16 *e1t20 = ub + 10551296;
        float* base0 = p_h1;          // reuse p_h1 after epilogue2 consumed it
        float* base1 = p_h1 + 1048576;

        convertK2<<<dim3(1704), blk, 0, stream>>>(o, oW1, eW1, oW2, eW2, ob2,
                                                  eb1, o_bf, bW1t, bE1t, o2bf,
                                                  w2th, e1t20, biasWc);
        kernelA2<<<dim3(512), blk, 0, stream>>>(o_bf, bW1t, o2bf, bE1t,
                                                p_h1, p_wc);
        epilogue2<<<dim3(512), blk, 0, stream>>>(p_h1, p_wc, ob1, h1bf, Wct);
        kernelB2<<<dim3(256), blk, 0, stream>>>(h1bf, Wct, biasWc,
                                                base0, base1);
        chain_seq<<<dim3(B_), blk, 0, stream>>>(x, eW1, eW2, eb2,
                                                base0, base1, cur0b);
        expand<<<dim3(1344), blk, 0, stream>>>(x, base0, base1, cur0b, e1t20,
                                               w2th, eb2, outp);
    } else {
        const size_t MF = (size_t)H_ * H_;
        float* h1    = ws;
        float* Wc    = ws + MF;
        float* base0 = ws + 2 * MF;
        float* biasc = outp;
        kernelA_fb<<<dim3(544), blk, 0, stream>>>(o, oW1, ob1, oW2, eW1, ob2,
                                                  h1, Wc, biasc);
        kernelB_fb<<<dim3(256), blk, 0, stream>>>(h1, Wc, eb1, biasc, base0);
        expert_seq_fb<<<dim3(B_), blk, 0, stream>>>(x, eW1, eW2, eb2,
                                                    base0, outp);
    }
}